// Round 1
// baseline (649.026 us; speedup 1.0000x reference)
//
#include <hip/hip_runtime.h>
#include <hip/hip_bf16.h>
#include <cstdint>

typedef _Float16 half8 __attribute__((ext_vector_type(8)));
typedef float f32x4 __attribute__((ext_vector_type(4)));

// ---------------- fp32 -> f16 convert ----------------
__global__ __launch_bounds__(256) void conv_f16(const float* __restrict__ src,
                                                _Float16* __restrict__ dst, int n) {
  int i = (blockIdx.x * 256 + threadIdx.x) * 4;
  if (i + 3 < n) {
    float4 v = *reinterpret_cast<const float4*>(src + i);
    dst[i + 0] = (_Float16)v.x;
    dst[i + 1] = (_Float16)v.y;
    dst[i + 2] = (_Float16)v.z;
    dst[i + 3] = (_Float16)v.w;
  }
}

// ---------------- tiled transpose fp32[R][C] -> f16[C][R] ----------------
__global__ __launch_bounds__(256) void transpose_f16(const float* __restrict__ src,
                                                     _Float16* __restrict__ dst,
                                                     int R, int C) {
  __shared__ float tile[32][33];
  int c0 = blockIdx.x * 32, r0 = blockIdx.y * 32;
  int x = threadIdx.x & 31, y = threadIdx.x >> 5;  // 32 x 8
#pragma unroll
  for (int j = 0; j < 4; ++j)
    tile[y + j * 8][x] = src[(long)(r0 + y + j * 8) * C + c0 + x];
  __syncthreads();
#pragma unroll
  for (int j = 0; j < 4; ++j)
    dst[(long)(c0 + y + j * 8) * R + r0 + x] = (_Float16)tile[x][y + j * 8];
}

// ---------------- GEMM: C[M][N] = A[M][K] * BT[N][K]^T ----------------
// 128x128 tile, BK=64, 4 waves (2x2), each wave 64x64 via 4x4 16x16x32 MFMA frags.
template <bool OUTF32>
__global__ __launch_bounds__(256) void gemm_bt(const _Float16* __restrict__ A, int lda,
                                               const _Float16* __restrict__ BT, int ldb,
                                               void* __restrict__ Cv, int ldc, int K) {
  __shared__ alignas(16) char As[128 * 64 * 2];
  __shared__ alignas(16) char Bs[128 * 64 * 2];
  const int tid = threadIdx.x;
  const int lane = tid & 63;
  const int wave = tid >> 6;
  const int wm = wave >> 1, wn = wave & 1;
  const int m0 = blockIdx.y * 128, n0 = blockIdx.x * 128;
  f32x4 acc[4][4] = {};
  int srow[4], scol[4];
#pragma unroll
  for (int j = 0; j < 4; ++j) {
    int i = j * 256 + tid;
    srow[j] = i >> 3;   // 0..127
    scol[j] = i & 7;    // 16B chunk within 128B row
  }
  for (int k0 = 0; k0 < K; k0 += 64) {
    half8 ra[4], rb[4];
#pragma unroll
    for (int j = 0; j < 4; ++j)
      ra[j] = *reinterpret_cast<const half8*>(A + (long)(m0 + srow[j]) * lda + k0 + scol[j] * 8);
#pragma unroll
    for (int j = 0; j < 4; ++j)
      rb[j] = *reinterpret_cast<const half8*>(BT + (long)(n0 + srow[j]) * ldb + k0 + scol[j] * 8);
    __syncthreads();  // previous tile's compute done before overwrite
#pragma unroll
    for (int j = 0; j < 4; ++j) {
      int b = (srow[j] * 128 + scol[j] * 16) ^ ((srow[j] & 7) << 4);
      *reinterpret_cast<half8*>(As + b) = ra[j];
      *reinterpret_cast<half8*>(Bs + b) = rb[j];
    }
    __syncthreads();
#pragma unroll
    for (int kk = 0; kk < 2; ++kk) {
      half8 af[4], bf[4];
#pragma unroll
      for (int mi = 0; mi < 4; ++mi) {
        int row = wm * 64 + mi * 16 + (lane & 15);
        int b = (row * 128 + kk * 64 + ((lane >> 4) * 16)) ^ ((row & 7) << 4);
        af[mi] = *reinterpret_cast<const half8*>(As + b);
      }
#pragma unroll
      for (int ni = 0; ni < 4; ++ni) {
        int row = wn * 64 + ni * 16 + (lane & 15);
        int b = (row * 128 + kk * 64 + ((lane >> 4) * 16)) ^ ((row & 7) << 4);
        bf[ni] = *reinterpret_cast<const half8*>(Bs + b);
      }
#pragma unroll
      for (int mi = 0; mi < 4; ++mi)
#pragma unroll
        for (int ni = 0; ni < 4; ++ni)
          acc[mi][ni] =
              __builtin_amdgcn_mfma_f32_16x16x32_f16(af[mi], bf[ni], acc[mi][ni], 0, 0, 0);
    }
  }
  // C write: row = (lane>>4)*4 + r, col = lane&15  (verified C/D layout)
#pragma unroll
  for (int mi = 0; mi < 4; ++mi) {
#pragma unroll
    for (int ni = 0; ni < 4; ++ni) {
      int row = m0 + wm * 64 + mi * 16 + ((lane >> 4) << 2);
      int col = n0 + wn * 64 + ni * 16 + (lane & 15);
      f32x4 v = acc[mi][ni];
#pragma unroll
      for (int r = 0; r < 4; ++r) {
        if constexpr (OUTF32)
          reinterpret_cast<float*>(Cv)[(long)(row + r) * ldc + col] = v[r];
        else
          reinterpret_cast<_Float16*>(Cv)[(long)(row + r) * ldc + col] = (_Float16)v[r];
      }
    }
  }
}

// ---------------- RoPE in-place on q and k ----------------
__global__ __launch_bounds__(256) void rope_k(_Float16* __restrict__ q,
                                              _Float16* __restrict__ k) {
  int idx = blockIdx.x * 256 + threadIdx.x;  // 2 * 4096 * 1024
  _Float16* p = (idx & (1 << 22)) ? k : q;
  int rem = idx & ((1 << 22) - 1);
  int row = rem >> 10;       // 0..4095 (b*2048+s)
  int pr = rem & 1023;       // h*64 + dp
  int hh = pr >> 6, dp = pr & 63;
  int s = row & 2047;
  float invf = exp2f(-(float)dp * (13.287712379549449f / 64.0f));  // theta^(-dp/64)
  float f = (float)s * invf;
  float cs = cosf(f), sn = sinf(f);
  long base = (long)row * 2048 + hh * 128 + dp;
  float x1 = (float)p[base], x2 = (float)p[base + 64];
  p[base] = (_Float16)(x1 * cs - x2 * sn);
  p[base + 64] = (_Float16)(x2 * cs + x1 * sn);
}

// ---------------- fused causal flash attention ----------------
// Layouts: Q/K/V/O all [b*2048+s][2048] f16, head h at columns h*128..h*128+127.
// Block = (q-tile of 64 rows, head, batch); 4 waves x 16 q-rows; KV tiles of 32.
__global__ __launch_bounds__(256) void attn_fused(const _Float16* __restrict__ Q,
                                                  const _Float16* __restrict__ Kt,
                                                  const _Float16* __restrict__ V,
                                                  _Float16* __restrict__ O) {
  __shared__ alignas(16) char Ks[32 * 256];        // swizzled [32 keys][128 d]
  __shared__ alignas(16) _Float16 Vt[128 * 40];    // V^T [d][key], row pad to 40
  __shared__ alignas(16) _Float16 Ps[4][16 * 40];  // per-wave P [16 q][32 k], pad 40
  const int tid = threadIdx.x, lane = tid & 63, wave = tid >> 6;
  const int qt = blockIdx.x, h = blockIdx.y, b = blockIdx.z;
  const long rowbase = (long)b * 2048;
  const int q0 = qt * 64;
  const int colbase = h * 128;

  half8 qf[4];
  {
    int qrow = q0 + wave * 16 + (lane & 15);
    const _Float16* qp = Q + (rowbase + qrow) * 2048 + colbase + ((lane >> 4) * 8);
#pragma unroll
    for (int c = 0; c < 4; ++c) qf[c] = *reinterpret_cast<const half8*>(qp + c * 32);
  }
  f32x4 o_acc[8] = {};
  float m_i[4] = {-INFINITY, -INFINITY, -INFINITY, -INFINITY};
  float l_i[4] = {0.f, 0.f, 0.f, 0.f};
  const float scale = 0.08838834764831845f;  // 1/sqrt(128)
  const int nk = q0 + 64;
  _Float16* Psw = &Ps[wave][0];

  for (int k0 = 0; k0 < nk; k0 += 32) {
    half8 rk[2], rv[2];
    int kr[2], kc[2];
#pragma unroll
    for (int j = 0; j < 2; ++j) {
      int i = j * 256 + tid;
      kr[j] = i >> 4;   // key row 0..31
      kc[j] = i & 15;   // 16B chunk within 256B row
      rk[j] = *reinterpret_cast<const half8*>(Kt + (rowbase + k0 + kr[j]) * 2048 + colbase + kc[j] * 8);
      rv[j] = *reinterpret_cast<const half8*>(V + (rowbase + k0 + kr[j]) * 2048 + colbase + kc[j] * 8);
    }
    __syncthreads();  // all waves done with previous tile
#pragma unroll
    for (int j = 0; j < 2; ++j) {
      int bo = (kr[j] * 256 + kc[j] * 16) ^ ((kr[j] & 7) << 4);
      *reinterpret_cast<half8*>(Ks + bo) = rk[j];
      int d0 = kc[j] * 8;
#pragma unroll
      for (int e = 0; e < 8; ++e) Vt[(d0 + e) * 40 + kr[j]] = rv[j][e];
    }
    __syncthreads();

    // S = Q K^T  (M=16 q, N=2x16 keys, K=128)
    f32x4 sacc[2] = {};
#pragma unroll
    for (int n = 0; n < 2; ++n) {
      int key = n * 16 + (lane & 15);
#pragma unroll
      for (int c = 0; c < 4; ++c) {
        int bo = (key * 256 + c * 64 + ((lane >> 4) * 16)) ^ ((key & 7) << 4);
        half8 kf = *reinterpret_cast<const half8*>(Ks + bo);
        sacc[n] = __builtin_amdgcn_mfma_f32_16x16x32_f16(qf[c], kf, sacc[n], 0, 0, 0);
      }
    }
    // online softmax (rows = (lane>>4)*4 + r; cols = lane&15 within each 16-tile)
    float alpha_[4];
#pragma unroll
    for (int r = 0; r < 4; ++r) {
      int qrow_r = q0 + wave * 16 + ((lane >> 4) << 2) + r;
      float s0 = sacc[0][r] * scale;
      float s1 = sacc[1][r] * scale;
      int key0 = k0 + (lane & 15);
      if (key0 > qrow_r) s0 = -INFINITY;
      if (key0 + 16 > qrow_r) s1 = -INFINITY;
      float mx = fmaxf(s0, s1);
#pragma unroll
      for (int off = 8; off; off >>= 1) mx = fmaxf(mx, __shfl_xor(mx, off));
      float mnew = fmaxf(m_i[r], mx);
      alpha_[r] = expf(m_i[r] - mnew);
      float p0 = expf(s0 - mnew), p1 = expf(s1 - mnew);
      float ls = p0 + p1;
#pragma unroll
      for (int off = 8; off; off >>= 1) ls += __shfl_xor(ls, off);
      l_i[r] = l_i[r] * alpha_[r] + ls;
      m_i[r] = mnew;
      int prow = ((lane >> 4) << 2) + r;
      Psw[prow * 40 + (lane & 15)] = (_Float16)p0;
      Psw[prow * 40 + 16 + (lane & 15)] = (_Float16)p1;
    }
#pragma unroll
    for (int n = 0; n < 8; ++n) {
      f32x4 t = o_acc[n];
      t[0] *= alpha_[0]; t[1] *= alpha_[1]; t[2] *= alpha_[2]; t[3] *= alpha_[3];
      o_acc[n] = t;
    }
    // O += P V  (M=16 q, N=8x16 d, K=32 keys)
    half8 pf = *reinterpret_cast<const half8*>(Psw + (lane & 15) * 40 + ((lane >> 4) * 8));
#pragma unroll
    for (int n = 0; n < 8; ++n) {
      int d = n * 16 + (lane & 15);
      half8 vf = *reinterpret_cast<const half8*>(&Vt[d * 40 + ((lane >> 4) * 8)]);
      o_acc[n] = __builtin_amdgcn_mfma_f32_16x16x32_f16(pf, vf, o_acc[n], 0, 0, 0);
    }
  }
  // epilogue
#pragma unroll
  for (int n = 0; n < 8; ++n) {
    int d = colbase + n * 16 + (lane & 15);
#pragma unroll
    for (int r = 0; r < 4; ++r) {
      int row = q0 + wave * 16 + ((lane >> 4) << 2) + r;
      O[(rowbase + row) * 2048 + d] = (_Float16)(o_acc[n][r] / l_i[r]);
    }
  }
}

extern "C" void kernel_launch(void* const* d_in, const int* in_sizes, int n_in,
                              void* d_out, int out_size, void* d_ws, size_t ws_size,
                              hipStream_t stream) {
  const float* x     = (const float*)d_in[0];
  const float* Wq_d  = (const float*)d_in[1];  // [2048][512]
  const float* Wkv_d = (const float*)d_in[2];  // [2048][512]
  const float* Wq_u  = (const float*)d_in[3];  // [512][2048]
  const float* Wk_u  = (const float*)d_in[4];  // [512][2048]
  const float* Wv_u  = (const float*)d_in[5];  // [512][2048]
  const float* Wo    = (const float*)d_in[6];  // [2048][2048]
  char* ws = (char*)d_ws;
  _Float16* xb  = (_Float16*)(ws);              // [4096][2048] (reused as ao)
  _Float16* wdT = (_Float16*)(ws + 16777216);   // [1024][2048]  (Wq_d^T ; Wkv_d^T)
  _Float16* wuT = (_Float16*)(ws + 20971520);   // 3x [2048][512]
  _Float16* woT = (_Float16*)(ws + 27262976);   // [2048][2048]
  _Float16* lat = (_Float16*)(ws + 35651584);   // [4096][1024]
  _Float16* qb  = (_Float16*)(ws + 44040192);   // [4096][2048]
  _Float16* kb  = (_Float16*)(ws + 60817408);   // [4096][2048]
  _Float16* vb  = (_Float16*)(ws + 77594624);   // [4096][2048]
  _Float16* ao  = xb;

  conv_f16<<<8192, 256, 0, stream>>>(x, xb, 8388608);
  transpose_f16<<<dim3(16, 64), 256, 0, stream>>>(Wq_d, wdT, 2048, 512);
  transpose_f16<<<dim3(16, 64), 256, 0, stream>>>(Wkv_d, wdT + 512 * 2048, 2048, 512);
  transpose_f16<<<dim3(64, 16), 256, 0, stream>>>(Wq_u, wuT, 512, 2048);
  transpose_f16<<<dim3(64, 16), 256, 0, stream>>>(Wk_u, wuT + 2048 * 512, 512, 2048);
  transpose_f16<<<dim3(64, 16), 256, 0, stream>>>(Wv_u, wuT + 2 * 2048 * 512, 512, 2048);
  transpose_f16<<<dim3(64, 64), 256, 0, stream>>>(Wo, woT, 2048, 2048);

  // lat = x @ [Wq_d | Wkv_d]   (M=4096, N=1024, K=2048)
  gemm_bt<false><<<dim3(8, 32), 256, 0, stream>>>(xb, 2048, wdT, 2048, lat, 1024, 2048);
  // q/k/v = lat(.,latpart) @ W*_u  (M=4096, N=2048, K=512)
  gemm_bt<false><<<dim3(16, 32), 256, 0, stream>>>(lat, 1024, wuT, 512, qb, 2048, 512);
  gemm_bt<false><<<dim3(16, 32), 256, 0, stream>>>(lat + 512, 1024, wuT + 2048 * 512, 512, kb, 2048, 512);
  gemm_bt<false><<<dim3(16, 32), 256, 0, stream>>>(lat + 512, 1024, wuT + 2 * 2048 * 512, 512, vb, 2048, 512);

  rope_k<<<32768, 256, 0, stream>>>(qb, kb);
  attn_fused<<<dim3(32, 16, 2), 256, 0, stream>>>(qb, kb, vb, ao);

  // out = ao @ Wo  (fp32 store)
  gemm_bt<true><<<dim3(16, 32), 256, 0, stream>>>(ao, 2048, woT, 2048, d_out, 2048, 2048);
}

// Round 2
// 367.668 us; speedup vs baseline: 1.7653x; 1.7653x over previous
//
#include <hip/hip_runtime.h>
#include <hip/hip_bf16.h>
#include <cstdint>

typedef _Float16 half8 __attribute__((ext_vector_type(8)));
typedef float f32x4 __attribute__((ext_vector_type(4)));

// ---------------- fp32 -> f16 convert ----------------
__global__ __launch_bounds__(256) void conv_f16(const float* __restrict__ src,
                                                _Float16* __restrict__ dst, int n) {
  int i = (blockIdx.x * 256 + threadIdx.x) * 4;
  if (i + 3 < n) {
    float4 v = *reinterpret_cast<const float4*>(src + i);
    dst[i + 0] = (_Float16)v.x;
    dst[i + 1] = (_Float16)v.y;
    dst[i + 2] = (_Float16)v.z;
    dst[i + 3] = (_Float16)v.w;
  }
}

// ---------------- tiled transpose fp32[R][C] -> f16[C][R] ----------------
__global__ __launch_bounds__(256) void transpose_f16(const float* __restrict__ src,
                                                     _Float16* __restrict__ dst,
                                                     int R, int C) {
  __shared__ float tile[32][33];
  int c0 = blockIdx.x * 32, r0 = blockIdx.y * 32;
  int x = threadIdx.x & 31, y = threadIdx.x >> 5;  // 32 x 8
#pragma unroll
  for (int j = 0; j < 4; ++j)
    tile[y + j * 8][x] = src[(long)(r0 + y + j * 8) * C + c0 + x];
  __syncthreads();
#pragma unroll
  for (int j = 0; j < 4; ++j)
    dst[(long)(c0 + y + j * 8) * R + r0 + x] = (_Float16)tile[x][y + j * 8];
}

// ---------------- GEMM: C[M][N] = A[M][K] * BT[N][K]^T ----------------
// 128x128 tile, BK=64, 4 waves (2x2), each wave 64x64 via 4x4 16x16x32 MFMA frags.
template <bool OUTF32>
__global__ __launch_bounds__(256) void gemm_bt(const _Float16* __restrict__ A, int lda,
                                               const _Float16* __restrict__ BT, int ldb,
                                               void* __restrict__ Cv, int ldc, int K) {
  __shared__ alignas(16) char As[128 * 64 * 2];
  __shared__ alignas(16) char Bs[128 * 64 * 2];
  const int tid = threadIdx.x;
  const int lane = tid & 63;
  const int wave = tid >> 6;
  const int wm = wave >> 1, wn = wave & 1;
  const int m0 = blockIdx.y * 128, n0 = blockIdx.x * 128;
  f32x4 acc[4][4] = {};
  int srow[4], scol[4];
#pragma unroll
  for (int j = 0; j < 4; ++j) {
    int i = j * 256 + tid;
    srow[j] = i >> 3;   // 0..127
    scol[j] = i & 7;    // 16B chunk within 128B row
  }
  for (int k0 = 0; k0 < K; k0 += 64) {
    half8 ra[4], rb[4];
#pragma unroll
    for (int j = 0; j < 4; ++j)
      ra[j] = *reinterpret_cast<const half8*>(A + (long)(m0 + srow[j]) * lda + k0 + scol[j] * 8);
#pragma unroll
    for (int j = 0; j < 4; ++j)
      rb[j] = *reinterpret_cast<const half8*>(BT + (long)(n0 + srow[j]) * ldb + k0 + scol[j] * 8);
    __syncthreads();  // previous tile's compute done before overwrite
#pragma unroll
    for (int j = 0; j < 4; ++j) {
      int b = (srow[j] * 128 + scol[j] * 16) ^ ((srow[j] & 7) << 4);
      *reinterpret_cast<half8*>(As + b) = ra[j];
      *reinterpret_cast<half8*>(Bs + b) = rb[j];
    }
    __syncthreads();
#pragma unroll
    for (int kk = 0; kk < 2; ++kk) {
      half8 af[4], bf[4];
#pragma unroll
      for (int mi = 0; mi < 4; ++mi) {
        int row = wm * 64 + mi * 16 + (lane & 15);
        int b = (row * 128 + kk * 64 + ((lane >> 4) * 16)) ^ ((row & 7) << 4);
        af[mi] = *reinterpret_cast<const half8*>(As + b);
      }
#pragma unroll
      for (int ni = 0; ni < 4; ++ni) {
        int row = wn * 64 + ni * 16 + (lane & 15);
        int b = (row * 128 + kk * 64 + ((lane >> 4) * 16)) ^ ((row & 7) << 4);
        bf[ni] = *reinterpret_cast<const half8*>(Bs + b);
      }
#pragma unroll
      for (int mi = 0; mi < 4; ++mi)
#pragma unroll
        for (int ni = 0; ni < 4; ++ni)
          acc[mi][ni] =
              __builtin_amdgcn_mfma_f32_16x16x32_f16(af[mi], bf[ni], acc[mi][ni], 0, 0, 0);
    }
  }
  // C write: row = (lane>>4)*4 + r, col = lane&15
#pragma unroll
  for (int mi = 0; mi < 4; ++mi) {
#pragma unroll
    for (int ni = 0; ni < 4; ++ni) {
      int row = m0 + wm * 64 + mi * 16 + ((lane >> 4) << 2);
      int col = n0 + wn * 64 + ni * 16 + (lane & 15);
      f32x4 v = acc[mi][ni];
#pragma unroll
      for (int r = 0; r < 4; ++r) {
        if constexpr (OUTF32)
          reinterpret_cast<float*>(Cv)[(long)(row + r) * ldc + col] = v[r];
        else
          reinterpret_cast<_Float16*>(Cv)[(long)(row + r) * ldc + col] = (_Float16)v[r];
      }
    }
  }
}

// ---------------- RoPE in-place on q and k ----------------
__global__ __launch_bounds__(256) void rope_k(_Float16* __restrict__ q,
                                              _Float16* __restrict__ k) {
  int idx = blockIdx.x * 256 + threadIdx.x;  // 2 * 4096 * 1024
  _Float16* p = (idx & (1 << 22)) ? k : q;
  int rem = idx & ((1 << 22) - 1);
  int row = rem >> 10;       // 0..4095 (b*2048+s)
  int pr = rem & 1023;       // h*64 + dp
  int hh = pr >> 6, dp = pr & 63;
  int s = row & 2047;
  float invf = exp2f(-(float)dp * (13.287712379549449f / 64.0f));  // theta^(-dp/64)
  float f = (float)s * invf;
  float cs = cosf(f), sn = sinf(f);
  long base = (long)row * 2048 + hh * 128 + dp;
  float x1 = (float)p[base], x2 = (float)p[base + 64];
  p[base] = (_Float16)(x1 * cs - x2 * sn);
  p[base + 64] = (_Float16)(x2 * cs + x1 * sn);
}

// ---------------- fused causal flash attention (v2) ----------------
// Q/K/V/O: [b*2048+s][2048] f16, head h at cols h*128..h*128+127.
// Block = (q-tile 64 rows, head, batch), qt REVERSED (longest first).
// 4 waves x 16 q-rows; KV tiles of 64; double-buffered K/V LDS; async stage
// (T14: load-early / write-late); ONE barrier per tile.
// K LDS: linear [key][16B-chunk], chunk XOR-swizzled with key&7 (2-way = free).
// V LDS: V^T [d=128][key=64] stride 72 f16 (144B), 8-key chunks placed at
//        chunk ^ ((d>>3)&7) -> write scatter 16-way -> ~2-way.
__global__ __launch_bounds__(256) void attn_fused(const _Float16* __restrict__ Q,
                                                  const _Float16* __restrict__ Kt,
                                                  const _Float16* __restrict__ V,
                                                  _Float16* __restrict__ O) {
  __shared__ alignas(16) char Ks[2][64 * 256];        // 2 x 16 KB
  __shared__ alignas(16) _Float16 Vt[2][128 * 72];    // 2 x 18 KB
  __shared__ alignas(16) _Float16 Ps[4][16 * 72];     // per-wave P, 9 KB
  const int tid = threadIdx.x, lane = tid & 63, wave = tid >> 6;
  const int g = lane >> 4;   // 4-lane-group id (C-layout row group / k-chunk)
  const int qt = (int)(gridDim.x - 1 - blockIdx.x);   // longest blocks first
  const int h = blockIdx.y, b = blockIdx.z;
  const long rowbase = (long)b * 2048;
  const int q0 = qt * 64;
  const int colbase = h * 128;

  // Q fragments (held in registers for the whole kernel)
  half8 qf[4];
  {
    int qrow = q0 + wave * 16 + (lane & 15);
    const _Float16* qp = Q + (rowbase + qrow) * 2048 + colbase + (g * 8);
#pragma unroll
    for (int c = 0; c < 4; ++c) qf[c] = *reinterpret_cast<const half8*>(qp + c * 32);
  }
  f32x4 o_acc[8] = {};
  float m_i[4] = {-INFINITY, -INFINITY, -INFINITY, -INFINITY};
  float l_i[4] = {0.f, 0.f, 0.f, 0.f};
  const float scale = 0.08838834764831845f;  // 1/sqrt(128)
  _Float16* Psw = &Ps[wave][0];
  const int nt = qt + 1;  // number of 64-key tiles (causal)

  half8 rk[4], rv[4];
  int kr_[4], kc_[4];
#pragma unroll
  for (int j = 0; j < 4; ++j) {
    int idx = j * 256 + tid;
    kr_[j] = idx >> 4;   // key row 0..63
    kc_[j] = idx & 15;   // 16B chunk (8 d's)
  }

  auto stage_load = [&](int k0) {
#pragma unroll
    for (int j = 0; j < 4; ++j) {
      const _Float16* kp = Kt + (rowbase + k0 + kr_[j]) * 2048 + colbase + kc_[j] * 8;
      const _Float16* vp = V + (rowbase + k0 + kr_[j]) * 2048 + colbase + kc_[j] * 8;
      rk[j] = *reinterpret_cast<const half8*>(kp);
      rv[j] = *reinterpret_cast<const half8*>(vp);
    }
  };
  auto stage_write = [&](int buf) {
#pragma unroll
    for (int j = 0; j < 4; ++j) {
      int kr = kr_[j], kc = kc_[j];
      *reinterpret_cast<half8*>(Ks[buf] + kr * 256 + ((kc ^ (kr & 7)) * 16)) = rk[j];
      int cw = ((kr >> 3) ^ (kc & 7)) * 8 + (kr & 7);  // in-row position (f16)
      _Float16* vb_ = &Vt[buf][0];
#pragma unroll
      for (int e = 0; e < 8; ++e) vb_[(kc * 8 + e) * 72 + cw] = rv[j][e];
    }
  };

  // prologue: tile 0 into buffer 0
  stage_load(0);
  stage_write(0);
  __syncthreads();

  for (int t = 0; t < nt; ++t) {
    const int cur = t & 1;
    const bool pre = (t + 1) < nt;
    const int k0 = t * 64;
    if (pre) stage_load(k0 + 64);  // issue next tile's global loads early (T14)

    // ---- S = Q K^T : 4 key-frags x 4 k-slices ----
    f32x4 sacc[4] = {};
    __builtin_amdgcn_s_setprio(1);
#pragma unroll
    for (int n = 0; n < 4; ++n) {
      int key = n * 16 + (lane & 15);
#pragma unroll
      for (int c = 0; c < 4; ++c) {
        half8 kf = *reinterpret_cast<const half8*>(
            Ks[cur] + key * 256 + (((c * 4 + g) ^ (key & 7)) * 16));
        sacc[n] = __builtin_amdgcn_mfma_f32_16x16x32_f16(qf[c], kf, sacc[n], 0, 0, 0);
      }
    }
    __builtin_amdgcn_s_setprio(0);

    // ---- online softmax ----
    const bool diag = (t == nt - 1);
    float alpha_[4];
#pragma unroll
    for (int r = 0; r < 4; ++r) {
      int qrow_r = q0 + wave * 16 + (g << 2) + r;
      float s0 = sacc[0][r] * scale, s1 = sacc[1][r] * scale;
      float s2 = sacc[2][r] * scale, s3 = sacc[3][r] * scale;
      if (diag) {
        int key0 = k0 + (lane & 15);
        if (key0 > qrow_r) s0 = -INFINITY;
        if (key0 + 16 > qrow_r) s1 = -INFINITY;
        if (key0 + 32 > qrow_r) s2 = -INFINITY;
        if (key0 + 48 > qrow_r) s3 = -INFINITY;
      }
      float mx = fmaxf(fmaxf(s0, s1), fmaxf(s2, s3));
#pragma unroll
      for (int off = 8; off; off >>= 1) mx = fmaxf(mx, __shfl_xor(mx, off));
      float mnew = fmaxf(m_i[r], mx);
      alpha_[r] = __expf(m_i[r] - mnew);
      float p0 = __expf(s0 - mnew), p1 = __expf(s1 - mnew);
      float p2 = __expf(s2 - mnew), p3 = __expf(s3 - mnew);
      float ls = (p0 + p1) + (p2 + p3);
#pragma unroll
      for (int off = 8; off; off >>= 1) ls += __shfl_xor(ls, off);
      l_i[r] = l_i[r] * alpha_[r] + ls;
      m_i[r] = mnew;
      int prow = (g << 2) + r;
      Psw[prow * 72 + (lane & 15)] = (_Float16)p0;
      Psw[prow * 72 + 16 + (lane & 15)] = (_Float16)p1;
      Psw[prow * 72 + 32 + (lane & 15)] = (_Float16)p2;
      Psw[prow * 72 + 48 + (lane & 15)] = (_Float16)p3;
    }
#pragma unroll
    for (int n = 0; n < 8; ++n) {
      f32x4 tv = o_acc[n];
      tv[0] *= alpha_[0]; tv[1] *= alpha_[1]; tv[2] *= alpha_[2]; tv[3] *= alpha_[3];
      o_acc[n] = tv;
    }

    // ---- O += P V : 8 d-frags x 2 key-slices ----
    half8 pf[2];
#pragma unroll
    for (int ks = 0; ks < 2; ++ks)
      pf[ks] = *reinterpret_cast<const half8*>(Psw + (lane & 15) * 72 + ks * 32 + g * 8);
    const _Float16* vb_ = &Vt[cur][0];
    __builtin_amdgcn_s_setprio(1);
#pragma unroll
    for (int n = 0; n < 8; ++n) {
      int d = n * 16 + (lane & 15);
      int f = (d >> 3) & 7;
#pragma unroll
      for (int ks = 0; ks < 2; ++ks) {
        int cr = ks * 4 + g;
        half8 vf = *reinterpret_cast<const half8*>(&vb_[d * 72 + ((cr ^ f) * 8)]);
        o_acc[n] = __builtin_amdgcn_mfma_f32_16x16x32_f16(pf[ks], vf, o_acc[n], 0, 0, 0);
      }
    }
    __builtin_amdgcn_s_setprio(0);

    if (pre) stage_write((t + 1) & 1);  // write next tile's LDS (write-late)
    __syncthreads();
  }

  // epilogue
#pragma unroll
  for (int n = 0; n < 8; ++n) {
    int d = colbase + n * 16 + (lane & 15);
#pragma unroll
    for (int r = 0; r < 4; ++r) {
      int row = q0 + wave * 16 + (g << 2) + r;
      O[(rowbase + row) * 2048 + d] = (_Float16)(o_acc[n][r] / l_i[r]);
    }
  }
}

extern "C" void kernel_launch(void* const* d_in, const int* in_sizes, int n_in,
                              void* d_out, int out_size, void* d_ws, size_t ws_size,
                              hipStream_t stream) {
  const float* x     = (const float*)d_in[0];
  const float* Wq_d  = (const float*)d_in[1];  // [2048][512]
  const float* Wkv_d = (const float*)d_in[2];  // [2048][512]
  const float* Wq_u  = (const float*)d_in[3];  // [512][2048]
  const float* Wk_u  = (const float*)d_in[4];  // [512][2048]
  const float* Wv_u  = (const float*)d_in[5];  // [512][2048]
  const float* Wo    = (const float*)d_in[6];  // [2048][2048]
  char* ws = (char*)d_ws;
  _Float16* xb  = (_Float16*)(ws);              // [4096][2048] (reused as ao)
  _Float16* wdT = (_Float16*)(ws + 16777216);   // [1024][2048]  (Wq_d^T ; Wkv_d^T)
  _Float16* wuT = (_Float16*)(ws + 20971520);   // 3x [2048][512]
  _Float16* woT = (_Float16*)(ws + 27262976);   // [2048][2048]
  _Float16* lat = (_Float16*)(ws + 35651584);   // [4096][1024]
  _Float16* qb  = (_Float16*)(ws + 44040192);   // [4096][2048]
  _Float16* kb  = (_Float16*)(ws + 60817408);   // [4096][2048]
  _Float16* vb  = (_Float16*)(ws + 77594624);   // [4096][2048]
  _Float16* ao  = xb;

  conv_f16<<<8192, 256, 0, stream>>>(x, xb, 8388608);
  transpose_f16<<<dim3(16, 64), 256, 0, stream>>>(Wq_d, wdT, 2048, 512);
  transpose_f16<<<dim3(16, 64), 256, 0, stream>>>(Wkv_d, wdT + 512 * 2048, 2048, 512);
  transpose_f16<<<dim3(64, 16), 256, 0, stream>>>(Wq_u, wuT, 512, 2048);
  transpose_f16<<<dim3(64, 16), 256, 0, stream>>>(Wk_u, wuT + 2048 * 512, 512, 2048);
  transpose_f16<<<dim3(64, 16), 256, 0, stream>>>(Wv_u, wuT + 2 * 2048 * 512, 512, 2048);
  transpose_f16<<<dim3(64, 64), 256, 0, stream>>>(Wo, woT, 2048, 2048);

  // lat = x @ [Wq_d | Wkv_d]   (M=4096, N=1024, K=2048)
  gemm_bt<false><<<dim3(8, 32), 256, 0, stream>>>(xb, 2048, wdT, 2048, lat, 1024, 2048);
  // q/k/v = lat(.,latpart) @ W*_u  (M=4096, N=2048, K=512)
  gemm_bt<false><<<dim3(16, 32), 256, 0, stream>>>(lat, 1024, wuT, 512, qb, 2048, 512);
  gemm_bt<false><<<dim3(16, 32), 256, 0, stream>>>(lat + 512, 1024, wuT + 2048 * 512, 512, kb, 2048, 512);
  gemm_bt<false><<<dim3(16, 32), 256, 0, stream>>>(lat + 512, 1024, wuT + 2 * 2048 * 512, 512, vb, 2048, 512);

  rope_k<<<32768, 256, 0, stream>>>(qb, kb);
  attn_fused<<<dim3(32, 16, 2), 256, 0, stream>>>(qb, kb, vb, ao);

  // out = ao @ Wo  (fp32 store)
  gemm_bt<true><<<dim3(16, 32), 256, 0, stream>>>(ao, 2048, woT, 2048, d_out, 2048, 2048);
}

// Round 3
// 321.707 us; speedup vs baseline: 2.0174x; 1.1429x over previous
//
#include <hip/hip_runtime.h>
#include <hip/hip_bf16.h>
#include <cstdint>

typedef _Float16 half8 __attribute__((ext_vector_type(8)));
typedef float f32x4 __attribute__((ext_vector_type(4)));
typedef unsigned u32x4 __attribute__((ext_vector_type(4)));

// ---------------- fp32 -> f16 convert ----------------
__global__ __launch_bounds__(256) void conv_f16(const float* __restrict__ src,
                                                _Float16* __restrict__ dst, int n) {
  int i = (blockIdx.x * 256 + threadIdx.x) * 4;
  if (i + 3 < n) {
    float4 v = *reinterpret_cast<const float4*>(src + i);
    dst[i + 0] = (_Float16)v.x;
    dst[i + 1] = (_Float16)v.y;
    dst[i + 2] = (_Float16)v.z;
    dst[i + 3] = (_Float16)v.w;
  }
}

// ---------------- tiled transpose fp32[R][C] -> f16[C][R] ----------------
__global__ __launch_bounds__(256) void transpose_f16(const float* __restrict__ src,
                                                     _Float16* __restrict__ dst,
                                                     int R, int C) {
  __shared__ float tile[32][33];
  int c0 = blockIdx.x * 32, r0 = blockIdx.y * 32;
  int x = threadIdx.x & 31, y = threadIdx.x >> 5;  // 32 x 8
#pragma unroll
  for (int j = 0; j < 4; ++j)
    tile[y + j * 8][x] = src[(long)(r0 + y + j * 8) * C + c0 + x];
  __syncthreads();
#pragma unroll
  for (int j = 0; j < 4; ++j)
    dst[(long)(c0 + y + j * 8) * R + r0 + x] = (_Float16)tile[x][y + j * 8];
}

// ---------------- GEMM: C[M][N] = A[M][K] * BT[N][K]^T ----------------
template <bool OUTF32>
__global__ __launch_bounds__(256) void gemm_bt(const _Float16* __restrict__ A, int lda,
                                               const _Float16* __restrict__ BT, int ldb,
                                               void* __restrict__ Cv, int ldc, int K) {
  __shared__ alignas(16) char As[128 * 64 * 2];
  __shared__ alignas(16) char Bs[128 * 64 * 2];
  const int tid = threadIdx.x;
  const int lane = tid & 63;
  const int wave = tid >> 6;
  const int wm = wave >> 1, wn = wave & 1;
  const int m0 = blockIdx.y * 128, n0 = blockIdx.x * 128;
  f32x4 acc[4][4] = {};
  int srow[4], scol[4];
#pragma unroll
  for (int j = 0; j < 4; ++j) {
    int i = j * 256 + tid;
    srow[j] = i >> 3;
    scol[j] = i & 7;
  }
  for (int k0 = 0; k0 < K; k0 += 64) {
    half8 ra[4], rb[4];
#pragma unroll
    for (int j = 0; j < 4; ++j)
      ra[j] = *reinterpret_cast<const half8*>(A + (long)(m0 + srow[j]) * lda + k0 + scol[j] * 8);
#pragma unroll
    for (int j = 0; j < 4; ++j)
      rb[j] = *reinterpret_cast<const half8*>(BT + (long)(n0 + srow[j]) * ldb + k0 + scol[j] * 8);
    __syncthreads();
#pragma unroll
    for (int j = 0; j < 4; ++j) {
      int b = (srow[j] * 128 + scol[j] * 16) ^ ((srow[j] & 7) << 4);
      *reinterpret_cast<half8*>(As + b) = ra[j];
      *reinterpret_cast<half8*>(Bs + b) = rb[j];
    }
    __syncthreads();
#pragma unroll
    for (int kk = 0; kk < 2; ++kk) {
      half8 af[4], bf[4];
#pragma unroll
      for (int mi = 0; mi < 4; ++mi) {
        int row = wm * 64 + mi * 16 + (lane & 15);
        int b = (row * 128 + kk * 64 + ((lane >> 4) * 16)) ^ ((row & 7) << 4);
        af[mi] = *reinterpret_cast<const half8*>(As + b);
      }
#pragma unroll
      for (int ni = 0; ni < 4; ++ni) {
        int row = wn * 64 + ni * 16 + (lane & 15);
        int b = (row * 128 + kk * 64 + ((lane >> 4) * 16)) ^ ((row & 7) << 4);
        bf[ni] = *reinterpret_cast<const half8*>(Bs + b);
      }
#pragma unroll
      for (int mi = 0; mi < 4; ++mi)
#pragma unroll
        for (int ni = 0; ni < 4; ++ni)
          acc[mi][ni] =
              __builtin_amdgcn_mfma_f32_16x16x32_f16(af[mi], bf[ni], acc[mi][ni], 0, 0, 0);
    }
  }
#pragma unroll
  for (int mi = 0; mi < 4; ++mi) {
#pragma unroll
    for (int ni = 0; ni < 4; ++ni) {
      int row = m0 + wm * 64 + mi * 16 + ((lane >> 4) << 2);
      int col = n0 + wn * 64 + ni * 16 + (lane & 15);
      f32x4 v = acc[mi][ni];
#pragma unroll
      for (int r = 0; r < 4; ++r) {
        if constexpr (OUTF32)
          reinterpret_cast<float*>(Cv)[(long)(row + r) * ldc + col] = v[r];
        else
          reinterpret_cast<_Float16*>(Cv)[(long)(row + r) * ldc + col] = (_Float16)v[r];
      }
    }
  }
}

// ---------------- RoPE in-place on q and k ----------------
__global__ __launch_bounds__(256) void rope_k(_Float16* __restrict__ q,
                                              _Float16* __restrict__ k) {
  int idx = blockIdx.x * 256 + threadIdx.x;
  _Float16* p = (idx & (1 << 22)) ? k : q;
  int rem = idx & ((1 << 22) - 1);
  int row = rem >> 10;
  int pr = rem & 1023;
  int hh = pr >> 6, dp = pr & 63;
  int s = row & 2047;
  float invf = exp2f(-(float)dp * (13.287712379549449f / 64.0f));
  float f = (float)s * invf;
  float cs = cosf(f), sn = sinf(f);
  long base = (long)row * 2048 + hh * 128 + dp;
  float x1 = (float)p[base], x2 = (float)p[base + 64];
  p[base] = (_Float16)(x1 * cs - x2 * sn);
  p[base + 64] = (_Float16)(x2 * cs + x1 * sn);
}

// ---------------- fused causal flash attention (v3) ----------------
// Swapped QK^T (S^T = mfma(K,Q)): each lane owns the full 64-key P-row of
// q = lane&15 -> in-register softmax (tree + 2 shfl), P redistributed to PV
// A-fragments via cvt_pkrtz + permlane32/16_swap. No P LDS bounce.
__global__ __launch_bounds__(256) void attn_fused(const _Float16* __restrict__ Q,
                                                  const _Float16* __restrict__ Kt,
                                                  const _Float16* __restrict__ V,
                                                  _Float16* __restrict__ O) {
  __shared__ alignas(16) char Ks[2][64 * 256];      // 2 x 16 KB, chunk^(key&7) swizzle
  __shared__ alignas(16) _Float16 Vt[2][128 * 72];  // 2 x 18 KB, V^T with chunk xor
  const int tid = threadIdx.x, lane = tid & 63, wave = tid >> 6;
  const int g = lane >> 4;
  const int qt = (int)(gridDim.x - 1 - blockIdx.x);  // longest blocks first
  const int h = blockIdx.y, b = blockIdx.z;
  const long rowbase = (long)b * 2048;
  const int q0 = qt * 64;
  const int colbase = h * 128;
  const int qrow_own = q0 + wave * 16 + (lane & 15);

  // Q fragments, pre-scaled by 1/sqrt(d)
  half8 qf[4];
  {
    const _Float16* qp = Q + (rowbase + qrow_own) * 2048 + colbase + (g * 8);
    const _Float16 hs = (_Float16)0.08838834764831845f;
#pragma unroll
    for (int c = 0; c < 4; ++c) qf[c] = (*reinterpret_cast<const half8*>(qp + c * 32)) * hs;
  }
  f32x4 o_acc[8] = {};
  float m_own = -INFINITY, l_own = 0.f;             // per q = lane&15
  float mrow[4] = {-INFINITY, -INFINITY, -INFINITY, -INFINITY};  // per o_acc row
  const int nt = qt + 1;

  half8 rk[4], rv[4];
  int kr_[4], kc_[4];
#pragma unroll
  for (int j = 0; j < 4; ++j) {
    int idx = j * 256 + tid;
    kr_[j] = idx >> 4;
    kc_[j] = idx & 15;
  }

  auto stage_load = [&](int k0) {
#pragma unroll
    for (int j = 0; j < 4; ++j) {
      const _Float16* kp = Kt + (rowbase + k0 + kr_[j]) * 2048 + colbase + kc_[j] * 8;
      const _Float16* vp = V + (rowbase + k0 + kr_[j]) * 2048 + colbase + kc_[j] * 8;
      rk[j] = *reinterpret_cast<const half8*>(kp);
      rv[j] = *reinterpret_cast<const half8*>(vp);
    }
  };
  auto stage_write = [&](int buf) {
#pragma unroll
    for (int j = 0; j < 4; ++j) {
      int kr = kr_[j], kc = kc_[j];
      *reinterpret_cast<half8*>(Ks[buf] + kr * 256 + ((kc ^ (kr & 7)) * 16)) = rk[j];
      int cw = ((kr >> 3) ^ (kc & 7)) * 8 + (kr & 7);
      _Float16* vb_ = &Vt[buf][0];
#pragma unroll
      for (int e = 0; e < 8; ++e) vb_[(kc * 8 + e) * 72 + cw] = rv[j][e];
    }
  };

  stage_load(0);
  stage_write(0);
  __syncthreads();

  for (int t = 0; t < nt; ++t) {
    const int cur = t & 1;
    const bool pre = (t + 1) < nt;
    const int k0 = t * 64;
    if (pre) stage_load(k0 + 64);  // T14: issue next tile's global loads early

    // ---- S^T = K Q^T : sacc[n][r] = S[key = k0+n*16+g*4+r][q = lane&15] ----
    f32x4 sacc[4] = {};
    __builtin_amdgcn_s_setprio(1);
#pragma unroll
    for (int n = 0; n < 4; ++n) {
      int key = n * 16 + (lane & 15);
#pragma unroll
      for (int c = 0; c < 4; ++c) {
        half8 kf = *reinterpret_cast<const half8*>(
            Ks[cur] + key * 256 + (((c * 4 + g) ^ (key & 7)) * 16));
        sacc[n] = __builtin_amdgcn_mfma_f32_16x16x32_f16(kf, qf[c], sacc[n], 0, 0, 0);
      }
    }
    __builtin_amdgcn_s_setprio(0);

    // ---- causal mask (diag tile only) ----
    if (t == nt - 1) {
      int kb = k0 + g * 4 - qrow_own;
#pragma unroll
      for (int n = 0; n < 4; ++n)
#pragma unroll
        for (int r = 0; r < 4; ++r)
          if (kb + n * 16 + r > 0) sacc[n][r] = -INFINITY;
    }

    // ---- online softmax: in-lane tree + 2 shfl ----
    float a0 = fmaxf(fmaxf(sacc[0][0], sacc[0][1]), fmaxf(sacc[0][2], sacc[0][3]));
    float a1 = fmaxf(fmaxf(sacc[1][0], sacc[1][1]), fmaxf(sacc[1][2], sacc[1][3]));
    float a2 = fmaxf(fmaxf(sacc[2][0], sacc[2][1]), fmaxf(sacc[2][2], sacc[2][3]));
    float a3 = fmaxf(fmaxf(sacc[3][0], sacc[3][1]), fmaxf(sacc[3][2], sacc[3][3]));
    float mx = fmaxf(fmaxf(a0, a1), fmaxf(a2, a3));
    mx = fmaxf(mx, __shfl_xor(mx, 16));
    mx = fmaxf(mx, __shfl_xor(mx, 32));
    float mnew = fmaxf(m_own, mx);

    // redistribute new running max to o_acc rows (q = g*4+r)
    float alpha_[4];
#pragma unroll
    for (int r = 0; r < 4; ++r) {
      float mn = __shfl(mnew, (lane & 48) | (g * 4 + r));
      alpha_[r] = __expf(mrow[r] - mn);
      mrow[r] = mn;
    }

    float pexp[4][4];
#pragma unroll
    for (int n = 0; n < 4; ++n)
#pragma unroll
      for (int r = 0; r < 4; ++r) pexp[n][r] = __expf(sacc[n][r] - mnew);
    float s0 = (pexp[0][0] + pexp[0][1]) + (pexp[0][2] + pexp[0][3]);
    float s1 = (pexp[1][0] + pexp[1][1]) + (pexp[1][2] + pexp[1][3]);
    float s2 = (pexp[2][0] + pexp[2][1]) + (pexp[2][2] + pexp[2][3]);
    float s3 = (pexp[3][0] + pexp[3][1]) + (pexp[3][2] + pexp[3][3]);
    float ls = (s0 + s1) + (s2 + s3);
    ls += __shfl_xor(ls, 16);
    ls += __shfl_xor(ls, 32);
    l_own = l_own * __expf(m_own - mnew) + ls;
    m_own = mnew;

#pragma unroll
    for (int n = 0; n < 8; ++n) {
      f32x4 tv = o_acc[n];
      tv[0] *= alpha_[0]; tv[1] *= alpha_[1]; tv[2] *= alpha_[2]; tv[3] *= alpha_[3];
      o_acc[n] = tv;
    }

    // ---- P (f16, in-register) -> PV A-fragments via permlane swaps ----
    unsigned lo[4], hi[4];
#pragma unroll
    for (int n = 0; n < 4; ++n) {
      lo[n] = __builtin_bit_cast(unsigned, __builtin_amdgcn_cvt_pkrtz(pexp[n][0], pexp[n][1]));
      hi[n] = __builtin_bit_cast(unsigned, __builtin_amdgcn_cvt_pkrtz(pexp[n][2], pexp[n][3]));
    }
    half8 pa[2];
#pragma unroll
    for (int ks = 0; ks < 2; ++ks) {
      unsigned al = lo[ks * 2], bl = lo[ks * 2 + 1];
      unsigned ah = hi[ks * 2], bh = hi[ks * 2 + 1];
      asm("v_permlane32_swap_b32 %0, %1" : "+v"(al), "+v"(bl));
      asm("v_permlane16_swap_b32 %0, %1" : "+v"(al), "+v"(bl));
      asm("v_permlane32_swap_b32 %0, %1" : "+v"(ah), "+v"(bh));
      asm("v_permlane16_swap_b32 %0, %1" : "+v"(ah), "+v"(bh));
      u32x4 w;
      w[0] = al; w[1] = ah; w[2] = bl; w[3] = bh;
      pa[ks] = __builtin_bit_cast(half8, w);
    }

    // ---- O += P V ----
    const _Float16* vb_ = &Vt[cur][0];
    __builtin_amdgcn_s_setprio(1);
#pragma unroll
    for (int n = 0; n < 8; ++n) {
      int d = n * 16 + (lane & 15);
      int f = (d >> 3) & 7;
#pragma unroll
      for (int ks = 0; ks < 2; ++ks) {
        int cr = ks * 4 + g;
        half8 vf = *reinterpret_cast<const half8*>(&vb_[d * 72 + ((cr ^ f) * 8)]);
        o_acc[n] = __builtin_amdgcn_mfma_f32_16x16x32_f16(pa[ks], vf, o_acc[n], 0, 0, 0);
      }
    }
    __builtin_amdgcn_s_setprio(0);

    if (pre) stage_write((t + 1) & 1);  // write-late
    __syncthreads();
  }

  // epilogue: fetch l for o_acc rows, divide, store
  float lrow[4];
#pragma unroll
  for (int r = 0; r < 4; ++r) lrow[r] = __shfl(l_own, (lane & 48) | (g * 4 + r));
#pragma unroll
  for (int n = 0; n < 8; ++n) {
    int d = colbase + n * 16 + (lane & 15);
#pragma unroll
    for (int r = 0; r < 4; ++r) {
      int row = q0 + wave * 16 + (g << 2) + r;
      O[(rowbase + row) * 2048 + d] = (_Float16)(o_acc[n][r] / lrow[r]);
    }
  }
}

extern "C" void kernel_launch(void* const* d_in, const int* in_sizes, int n_in,
                              void* d_out, int out_size, void* d_ws, size_t ws_size,
                              hipStream_t stream) {
  const float* x     = (const float*)d_in[0];
  const float* Wq_d  = (const float*)d_in[1];
  const float* Wkv_d = (const float*)d_in[2];
  const float* Wq_u  = (const float*)d_in[3];
  const float* Wk_u  = (const float*)d_in[4];
  const float* Wv_u  = (const float*)d_in[5];
  const float* Wo    = (const float*)d_in[6];
  char* ws = (char*)d_ws;
  _Float16* xb  = (_Float16*)(ws);              // [4096][2048] (reused as ao)
  _Float16* wdT = (_Float16*)(ws + 16777216);   // [1024][2048]
  _Float16* wuT = (_Float16*)(ws + 20971520);   // 3x [2048][512]
  _Float16* woT = (_Float16*)(ws + 27262976);   // [2048][2048]
  _Float16* lat = (_Float16*)(ws + 35651584);   // [4096][1024]
  _Float16* qb  = (_Float16*)(ws + 44040192);   // [4096][2048]
  _Float16* kb  = (_Float16*)(ws + 60817408);   // [4096][2048]
  _Float16* vb  = (_Float16*)(ws + 77594624);   // [4096][2048]
  _Float16* ao  = xb;

  conv_f16<<<8192, 256, 0, stream>>>(x, xb, 8388608);
  transpose_f16<<<dim3(16, 64), 256, 0, stream>>>(Wq_d, wdT, 2048, 512);
  transpose_f16<<<dim3(16, 64), 256, 0, stream>>>(Wkv_d, wdT + 512 * 2048, 2048, 512);
  transpose_f16<<<dim3(64, 16), 256, 0, stream>>>(Wq_u, wuT, 512, 2048);
  transpose_f16<<<dim3(64, 16), 256, 0, stream>>>(Wk_u, wuT + 2048 * 512, 512, 2048);
  transpose_f16<<<dim3(64, 16), 256, 0, stream>>>(Wv_u, wuT + 2 * 2048 * 512, 512, 2048);
  transpose_f16<<<dim3(64, 64), 256, 0, stream>>>(Wo, woT, 2048, 2048);

  gemm_bt<false><<<dim3(8, 32), 256, 0, stream>>>(xb, 2048, wdT, 2048, lat, 1024, 2048);
  gemm_bt<false><<<dim3(16, 32), 256, 0, stream>>>(lat, 1024, wuT, 512, qb, 2048, 512);
  gemm_bt<false><<<dim3(16, 32), 256, 0, stream>>>(lat + 512, 1024, wuT + 2048 * 512, 512, kb, 2048, 512);
  gemm_bt<false><<<dim3(16, 32), 256, 0, stream>>>(lat + 512, 1024, wuT + 2 * 2048 * 512, 512, vb, 2048, 512);

  rope_k<<<32768, 256, 0, stream>>>(qb, kb);
  attn_fused<<<dim3(32, 16, 2), 256, 0, stream>>>(qb, kb, vb, ao);

  gemm_bt<true><<<dim3(16, 32), 256, 0, stream>>>(ao, 2048, woT, 2048, d_out, 2048, 2048);
}

// Round 4
// 257.695 us; speedup vs baseline: 2.5186x; 1.2484x over previous
//
#include <hip/hip_runtime.h>
#include <hip/hip_bf16.h>
#include <cstdint>

typedef _Float16 half8 __attribute__((ext_vector_type(8)));
typedef float f32x4 __attribute__((ext_vector_type(4)));
typedef unsigned u32x4 __attribute__((ext_vector_type(4)));

__device__ __forceinline__ void gload16(const void* g, void* l) {
  __builtin_amdgcn_global_load_lds((__attribute__((address_space(1))) void*)(g),
                                   (__attribute__((address_space(3))) void*)(l), 16, 0, 0);
}

// ---------------- fp32 -> f16 convert ----------------
__global__ __launch_bounds__(256) void conv_f16(const float* __restrict__ src,
                                                _Float16* __restrict__ dst, int n) {
  int i = (blockIdx.x * 256 + threadIdx.x) * 4;
  if (i + 3 < n) {
    float4 v = *reinterpret_cast<const float4*>(src + i);
    dst[i + 0] = (_Float16)v.x;
    dst[i + 1] = (_Float16)v.y;
    dst[i + 2] = (_Float16)v.z;
    dst[i + 3] = (_Float16)v.w;
  }
}

// ---------------- tiled transpose fp32[R][C] -> f16[C][R] ----------------
__global__ __launch_bounds__(256) void transpose_f16(const float* __restrict__ src,
                                                     _Float16* __restrict__ dst,
                                                     int R, int C) {
  __shared__ float tile[32][33];
  int c0 = blockIdx.x * 32, r0 = blockIdx.y * 32;
  int x = threadIdx.x & 31, y = threadIdx.x >> 5;
#pragma unroll
  for (int j = 0; j < 4; ++j)
    tile[y + j * 8][x] = src[(long)(r0 + y + j * 8) * C + c0 + x];
  __syncthreads();
#pragma unroll
  for (int j = 0; j < 4; ++j)
    dst[(long)(c0 + y + j * 8) * R + r0 + x] = (_Float16)tile[x][y + j * 8];
}

// ---------------- GEMM: C[M][N] = A[M][K] * BT[N][K]^T ----------------
// 128x128 tile, BK=64, global_load_lds staging (linear dest + source-swizzle),
// XCD-aware block swizzle.
template <bool OUTF32>
__global__ __launch_bounds__(256) void gemm_bt(const _Float16* __restrict__ A, int lda,
                                               const _Float16* __restrict__ BT, int ldb,
                                               void* __restrict__ Cv, int ldc, int K) {
  __shared__ alignas(16) char As[128 * 128];
  __shared__ alignas(16) char Bs[128 * 128];
  const int tid = threadIdx.x;
  const int lane = tid & 63;
  const int wave = tid >> 6;
  const int wm = wave >> 1, wn = wave & 1;
  // XCD swizzle (grid size always %8 == 0 here)
  const int nwg = (int)(gridDim.x * gridDim.y);
  const int bid = (int)(blockIdx.y * gridDim.x + blockIdx.x);
  const int swz = (bid & 7) * (nwg >> 3) + (bid >> 3);
  const int m0 = (swz / (int)gridDim.x) * 128, n0 = (swz % (int)gridDim.x) * 128;
  f32x4 acc[4][4] = {};
  int srow[4], scs[4];
#pragma unroll
  for (int j = 0; j < 4; ++j) {
    int i = j * 256 + tid;
    srow[j] = i >> 3;
    scs[j] = (i & 7) ^ (srow[j] & 7);  // inverse-swizzled source chunk
  }
  for (int k0 = 0; k0 < K; k0 += 64) {
    __syncthreads();  // previous compute done before overwrite
#pragma unroll
    for (int j = 0; j < 4; ++j)
      gload16(A + (long)(m0 + srow[j]) * lda + k0 + scs[j] * 8, As + (j * 256 + tid) * 16);
#pragma unroll
    for (int j = 0; j < 4; ++j)
      gload16(BT + (long)(n0 + srow[j]) * ldb + k0 + scs[j] * 8, Bs + (j * 256 + tid) * 16);
    __syncthreads();  // vmcnt drained -> LDS ready
#pragma unroll
    for (int kk = 0; kk < 2; ++kk) {
      half8 af[4], bf[4];
#pragma unroll
      for (int mi = 0; mi < 4; ++mi) {
        int row = wm * 64 + mi * 16 + (lane & 15);
        int b = (row * 128 + kk * 64 + ((lane >> 4) * 16)) ^ ((row & 7) << 4);
        af[mi] = *reinterpret_cast<const half8*>(As + b);
      }
#pragma unroll
      for (int ni = 0; ni < 4; ++ni) {
        int row = wn * 64 + ni * 16 + (lane & 15);
        int b = (row * 128 + kk * 64 + ((lane >> 4) * 16)) ^ ((row & 7) << 4);
        bf[ni] = *reinterpret_cast<const half8*>(Bs + b);
      }
#pragma unroll
      for (int mi = 0; mi < 4; ++mi)
#pragma unroll
        for (int ni = 0; ni < 4; ++ni)
          acc[mi][ni] =
              __builtin_amdgcn_mfma_f32_16x16x32_f16(af[mi], bf[ni], acc[mi][ni], 0, 0, 0);
    }
  }
#pragma unroll
  for (int mi = 0; mi < 4; ++mi) {
#pragma unroll
    for (int ni = 0; ni < 4; ++ni) {
      int row = m0 + wm * 64 + mi * 16 + ((lane >> 4) << 2);
      int col = n0 + wn * 64 + ni * 16 + (lane & 15);
      f32x4 v = acc[mi][ni];
#pragma unroll
      for (int r = 0; r < 4; ++r) {
        if constexpr (OUTF32)
          reinterpret_cast<float*>(Cv)[(long)(row + r) * ldc + col] = v[r];
        else
          reinterpret_cast<_Float16*>(Cv)[(long)(row + r) * ldc + col] = (_Float16)v[r];
      }
    }
  }
}

// ---------------- RoPE in-place on q and k ----------------
__global__ __launch_bounds__(256) void rope_k(_Float16* __restrict__ q,
                                              _Float16* __restrict__ k) {
  int idx = blockIdx.x * 256 + threadIdx.x;
  _Float16* p = (idx & (1 << 22)) ? k : q;
  int rem = idx & ((1 << 22) - 1);
  int row = rem >> 10;
  int pr = rem & 1023;
  int hh = pr >> 6, dp = pr & 63;
  int s = row & 2047;
  float invf = exp2f(-(float)dp * (13.287712379549449f / 64.0f));
  float f = (float)s * invf;
  float cs = cosf(f), sn = sinf(f);
  long base = (long)row * 2048 + hh * 128 + dp;
  float x1 = (float)p[base], x2 = (float)p[base + 64];
  p[base] = (_Float16)(x1 * cs - x2 * sn);
  p[base + 64] = (_Float16)(x2 * cs + x1 * sn);
}

// ---------------- fused causal flash attention (v4) ----------------
// Q: [s][2048] row-major; K: [s][2048] row-major; VT: [2048 d][4096 s] (pre-transposed).
// Block = 128 q-rows; 4 waves x 32 q (2 groups of 16); KV tiles of 64, double-buffered,
// staged via global_load_lds (linear dest + source swizzle). Swapped QK^T ->
// in-register softmax; P via cvt_pkrtz + permlane; defer-max (THR=8).
__global__ __launch_bounds__(256, 2) void attn_fused(const _Float16* __restrict__ Q,
                                                     const _Float16* __restrict__ Kr,
                                                     const _Float16* __restrict__ VT,
                                                     _Float16* __restrict__ O) {
  __shared__ alignas(16) char Ks[2][64 * 256];    // [key][chunk^(key&7)]
  __shared__ alignas(16) char Vs[2][128 * 128];   // [d][chunk^(d&7)] of VT tile
  const int tid = threadIdx.x, lane = tid & 63, wave = tid >> 6;
  const int g = lane >> 4;
  const int qt = (int)(gridDim.x - 1 - blockIdx.x);  // longest first
  const int h = blockIdx.y, b = blockIdx.z;
  const long sbase = (long)b * 2048;
  const int q0 = qt * 128;
  const int colbase = h * 128;
  const int qa_own = q0 + wave * 32 + (lane & 15);
  const int qb_own = qa_own + 16;

  half8 qfa[4], qfb[4];
  {
    const _Float16 hs = (_Float16)0.08838834764831845f;
    const _Float16* qpa = Q + (sbase + qa_own) * 2048 + colbase + g * 8;
    const _Float16* qpb = Q + (sbase + qb_own) * 2048 + colbase + g * 8;
#pragma unroll
    for (int c = 0; c < 4; ++c) {
      qfa[c] = (*reinterpret_cast<const half8*>(qpa + c * 32)) * hs;
      qfb[c] = (*reinterpret_cast<const half8*>(qpb + c * 32)) * hs;
    }
  }
  f32x4 oa[8] = {}, ob[8] = {};
  float ma = -INFINITY, la = 0.f, mb = -INFINITY, lb = 0.f;
  float mra[4] = {-INFINITY, -INFINITY, -INFINITY, -INFINITY};
  float mrb[4] = {-INFINITY, -INFINITY, -INFINITY, -INFINITY};
  const int nt = 2 * qt + 2;

  int k_kr[4], k_cs[4], v_vr[4], v_cs[4];
#pragma unroll
  for (int j = 0; j < 4; ++j) {
    int ci = j * 256 + tid;
    k_kr[j] = ci >> 4;
    k_cs[j] = (ci & 15) ^ (k_kr[j] & 7);
    v_vr[j] = ci >> 3;
    v_cs[j] = (ci & 7) ^ (v_vr[j] & 7);
  }

  auto stage = [&](int k0, int buf) {
#pragma unroll
    for (int j = 0; j < 4; ++j)
      gload16(Kr + (sbase + k0 + k_kr[j]) * 2048 + colbase + k_cs[j] * 8,
              Ks[buf] + (j * 256 + tid) * 16);
#pragma unroll
    for (int j = 0; j < 4; ++j)
      gload16(VT + (long)(colbase + v_vr[j]) * 4096 + sbase + k0 + v_cs[j] * 8,
              Vs[buf] + (j * 256 + tid) * 16);
  };

  stage(0, 0);
  __syncthreads();

  for (int t = 0; t < nt; ++t) {
    const int cur = t & 1;
    const int k0 = t * 64;
    if (t + 1 < nt) stage(k0 + 64, cur ^ 1);  // async into other buffer

    const bool active = !(t == nt - 1 && wave < 2);
    if (active) {
      // ---- S^T = K Q^T for both q-groups (K-frag read once) ----
      f32x4 sa[4] = {}, sb[4] = {};
      __builtin_amdgcn_s_setprio(1);
#pragma unroll
      for (int n = 0; n < 4; ++n) {
        int key = n * 16 + (lane & 15);
#pragma unroll
        for (int c = 0; c < 4; ++c) {
          half8 kf = *reinterpret_cast<const half8*>(
              Ks[cur] + key * 256 + (((c * 4 + g) ^ (key & 7)) * 16));
          sa[n] = __builtin_amdgcn_mfma_f32_16x16x32_f16(kf, qfa[c], sa[n], 0, 0, 0);
          sb[n] = __builtin_amdgcn_mfma_f32_16x16x32_f16(kf, qfb[c], sb[n], 0, 0, 0);
        }
      }
      __builtin_amdgcn_s_setprio(0);

      // ---- causal mask (last two tiles only) ----
      if (t >= nt - 2) {
        int kba = k0 + g * 4 - qa_own;
        int kbb = kba - 16;
#pragma unroll
        for (int n = 0; n < 4; ++n)
#pragma unroll
          for (int r = 0; r < 4; ++r) {
            if (kba + n * 16 + r > 0) sa[n][r] = -INFINITY;
            if (kbb + n * 16 + r > 0) sb[n][r] = -INFINITY;
          }
      }

      // ---- online softmax, defer-max ----
      float mxa = fmaxf(fmaxf(fmaxf(sa[0][0], sa[0][1]), fmaxf(sa[0][2], sa[0][3])),
                        fmaxf(fmaxf(sa[1][0], sa[1][1]), fmaxf(sa[1][2], sa[1][3])));
      mxa = fmaxf(mxa, fmaxf(fmaxf(fmaxf(sa[2][0], sa[2][1]), fmaxf(sa[2][2], sa[2][3])),
                             fmaxf(fmaxf(sa[3][0], sa[3][1]), fmaxf(sa[3][2], sa[3][3]))));
      float mxb = fmaxf(fmaxf(fmaxf(sb[0][0], sb[0][1]), fmaxf(sb[0][2], sb[0][3])),
                        fmaxf(fmaxf(sb[1][0], sb[1][1]), fmaxf(sb[1][2], sb[1][3])));
      mxb = fmaxf(mxb, fmaxf(fmaxf(fmaxf(sb[2][0], sb[2][1]), fmaxf(sb[2][2], sb[2][3])),
                             fmaxf(fmaxf(sb[3][0], sb[3][1]), fmaxf(sb[3][2], sb[3][3]))));
      mxa = fmaxf(mxa, __shfl_xor(mxa, 16));
      mxa = fmaxf(mxa, __shfl_xor(mxa, 32));
      mxb = fmaxf(mxb, __shfl_xor(mxb, 16));
      mxb = fmaxf(mxb, __shfl_xor(mxb, 32));

      bool need = (mxa > ma + 8.f) || (mxb > mb + 8.f);
      if (__any(need)) {
        float mna = fmaxf(ma, mxa), mnb = fmaxf(mb, mxb);
        float alfa[4], alfb[4];
#pragma unroll
        for (int r = 0; r < 4; ++r) {
          float va = __shfl(mna, (lane & 48) | (g * 4 + r));
          alfa[r] = __expf(mra[r] - va);
          mra[r] = va;
          float vb = __shfl(mnb, (lane & 48) | (g * 4 + r));
          alfb[r] = __expf(mrb[r] - vb);
          mrb[r] = vb;
        }
        la *= __expf(ma - mna);
        lb *= __expf(mb - mnb);
        ma = mna;
        mb = mnb;
#pragma unroll
        for (int n = 0; n < 8; ++n) {
          f32x4 ta = oa[n], tb = ob[n];
          ta[0] *= alfa[0]; ta[1] *= alfa[1]; ta[2] *= alfa[2]; ta[3] *= alfa[3];
          tb[0] *= alfb[0]; tb[1] *= alfb[1]; tb[2] *= alfb[2]; tb[3] *= alfb[3];
          oa[n] = ta; ob[n] = tb;
        }
      }

      float pea[4][4], peb[4][4];
#pragma unroll
      for (int n = 0; n < 4; ++n)
#pragma unroll
        for (int r = 0; r < 4; ++r) {
          pea[n][r] = __expf(sa[n][r] - ma);
          peb[n][r] = __expf(sb[n][r] - mb);
        }
      {
        float lsa = 0.f, lsb = 0.f;
#pragma unroll
        for (int n = 0; n < 4; ++n)
#pragma unroll
          for (int r = 0; r < 4; ++r) { lsa += pea[n][r]; lsb += peb[n][r]; }
        lsa += __shfl_xor(lsa, 16);
        lsa += __shfl_xor(lsa, 32);
        lsb += __shfl_xor(lsb, 16);
        lsb += __shfl_xor(lsb, 32);
        la += lsa;
        lb += lsb;
      }

      // ---- pack P to f16 PV A-fragments via permlane swaps ----
      half8 paa[2], pab[2];
      {
        unsigned loa[4], hia[4], lob[4], hib[4];
#pragma unroll
        for (int n = 0; n < 4; ++n) {
          loa[n] = __builtin_bit_cast(unsigned, __builtin_amdgcn_cvt_pkrtz(pea[n][0], pea[n][1]));
          hia[n] = __builtin_bit_cast(unsigned, __builtin_amdgcn_cvt_pkrtz(pea[n][2], pea[n][3]));
          lob[n] = __builtin_bit_cast(unsigned, __builtin_amdgcn_cvt_pkrtz(peb[n][0], peb[n][1]));
          hib[n] = __builtin_bit_cast(unsigned, __builtin_amdgcn_cvt_pkrtz(peb[n][2], peb[n][3]));
        }
#pragma unroll
        for (int ks = 0; ks < 2; ++ks) {
          unsigned al = loa[ks * 2], bl = loa[ks * 2 + 1];
          unsigned ah = hia[ks * 2], bh = hia[ks * 2 + 1];
          asm("v_permlane32_swap_b32 %0, %1" : "+v"(al), "+v"(bl));
          asm("v_permlane16_swap_b32 %0, %1" : "+v"(al), "+v"(bl));
          asm("v_permlane32_swap_b32 %0, %1" : "+v"(ah), "+v"(bh));
          asm("v_permlane16_swap_b32 %0, %1" : "+v"(ah), "+v"(bh));
          u32x4 w; w[0] = al; w[1] = ah; w[2] = bl; w[3] = bh;
          paa[ks] = __builtin_bit_cast(half8, w);
          unsigned al2 = lob[ks * 2], bl2 = lob[ks * 2 + 1];
          unsigned ah2 = hib[ks * 2], bh2 = hib[ks * 2 + 1];
          asm("v_permlane32_swap_b32 %0, %1" : "+v"(al2), "+v"(bl2));
          asm("v_permlane16_swap_b32 %0, %1" : "+v"(al2), "+v"(bl2));
          asm("v_permlane32_swap_b32 %0, %1" : "+v"(ah2), "+v"(bh2));
          asm("v_permlane16_swap_b32 %0, %1" : "+v"(ah2), "+v"(bh2));
          u32x4 w2; w2[0] = al2; w2[1] = ah2; w2[2] = bl2; w2[3] = bh2;
          pab[ks] = __builtin_bit_cast(half8, w2);
        }
      }

      // ---- O += P V (V-frag read once, feeds both groups) ----
      __builtin_amdgcn_s_setprio(1);
#pragma unroll
      for (int n = 0; n < 8; ++n) {
        int d = n * 16 + (lane & 15);
#pragma unroll
        for (int ks = 0; ks < 2; ++ks) {
          half8 vf = *reinterpret_cast<const half8*>(
              Vs[cur] + d * 128 + (((ks * 4 + g) ^ (d & 7)) * 16));
          oa[n] = __builtin_amdgcn_mfma_f32_16x16x32_f16(paa[ks], vf, oa[n], 0, 0, 0);
          ob[n] = __builtin_amdgcn_mfma_f32_16x16x32_f16(pab[ks], vf, ob[n], 0, 0, 0);
        }
      }
      __builtin_amdgcn_s_setprio(0);
    }
    __syncthreads();  // compute(cur) done everywhere + stage(next) drained
  }

  // ---- epilogue ----
  float lra[4], lrb[4];
#pragma unroll
  for (int r = 0; r < 4; ++r) {
    lra[r] = __shfl(la, (lane & 48) | (g * 4 + r));
    lrb[r] = __shfl(lb, (lane & 48) | (g * 4 + r));
  }
#pragma unroll
  for (int n = 0; n < 8; ++n) {
    int d = colbase + n * 16 + (lane & 15);
#pragma unroll
    for (int r = 0; r < 4; ++r) {
      int rowa = q0 + wave * 32 + (g << 2) + r;
      O[(sbase + rowa) * 2048 + d] = (_Float16)(oa[n][r] / lra[r]);
      O[(sbase + rowa + 16) * 2048 + d] = (_Float16)(ob[n][r] / lrb[r]);
    }
  }
}

extern "C" void kernel_launch(void* const* d_in, const int* in_sizes, int n_in,
                              void* d_out, int out_size, void* d_ws, size_t ws_size,
                              hipStream_t stream) {
  const float* x     = (const float*)d_in[0];
  const float* Wq_d  = (const float*)d_in[1];
  const float* Wkv_d = (const float*)d_in[2];
  const float* Wq_u  = (const float*)d_in[3];
  const float* Wk_u  = (const float*)d_in[4];
  const float* Wv_u  = (const float*)d_in[5];
  const float* Wo    = (const float*)d_in[6];
  char* ws = (char*)d_ws;
  _Float16* xb  = (_Float16*)(ws);              // [4096][2048] (reused as ao)
  _Float16* wdT = (_Float16*)(ws + 16777216);   // [1024][2048]
  _Float16* wuT = (_Float16*)(ws + 20971520);   // 3x [2048][512]
  _Float16* woT = (_Float16*)(ws + 27262976);   // [2048][2048]
  _Float16* lat = (_Float16*)(ws + 35651584);   // [4096][1024]
  _Float16* qb  = (_Float16*)(ws + 44040192);   // [4096][2048]
  _Float16* kb  = (_Float16*)(ws + 60817408);   // [4096][2048]
  _Float16* vT  = (_Float16*)(ws + 77594624);   // [2048 d][4096 s]
  _Float16* ao  = xb;

  conv_f16<<<8192, 256, 0, stream>>>(x, xb, 8388608);
  transpose_f16<<<dim3(16, 64), 256, 0, stream>>>(Wq_d, wdT, 2048, 512);
  transpose_f16<<<dim3(16, 64), 256, 0, stream>>>(Wkv_d, wdT + 512 * 2048, 2048, 512);
  transpose_f16<<<dim3(64, 16), 256, 0, stream>>>(Wq_u, wuT, 512, 2048);
  transpose_f16<<<dim3(64, 16), 256, 0, stream>>>(Wk_u, wuT + 2048 * 512, 512, 2048);
  transpose_f16<<<dim3(64, 16), 256, 0, stream>>>(Wv_u, wuT + 2 * 2048 * 512, 512, 2048);
  transpose_f16<<<dim3(64, 64), 256, 0, stream>>>(Wo, woT, 2048, 2048);

  // lat = x @ [Wq_d | Wkv_d]
  gemm_bt<false><<<dim3(8, 32), 256, 0, stream>>>(xb, 2048, wdT, 2048, lat, 1024, 2048);
  // q = lat_q @ Wq_u ; k = lat_kv @ Wk_u   (row-major outputs)
  gemm_bt<false><<<dim3(16, 32), 256, 0, stream>>>(lat, 1024, wuT, 512, qb, 2048, 512);
  gemm_bt<false><<<dim3(16, 32), 256, 0, stream>>>(lat + 512, 1024, wuT + 2048 * 512, 512, kb, 2048, 512);
  // vT[d][s] = Wv_u^T @ lat_kv^T  (transposed output, same FLOPs)
  gemm_bt<false><<<dim3(32, 16), 256, 0, stream>>>(wuT + 2 * 2048 * 512, 512, lat + 512, 1024, vT, 4096, 512);

  rope_k<<<32768, 256, 0, stream>>>(qb, kb);
  attn_fused<<<dim3(16, 16, 2), 256, 0, stream>>>(qb, kb, vT, ao);

  gemm_bt<true><<<dim3(16, 32), 256, 0, stream>>>(ao, 2048, woT, 2048, d_out, 2048, 2048);
}

// Round 5
// 253.169 us; speedup vs baseline: 2.5636x; 1.0179x over previous
//
#include <hip/hip_runtime.h>
#include <hip/hip_bf16.h>
#include <cstdint>

typedef _Float16 half8 __attribute__((ext_vector_type(8)));
typedef float f32x4 __attribute__((ext_vector_type(4)));
typedef unsigned u32x4 __attribute__((ext_vector_type(4)));

__device__ __forceinline__ void gload16(const void* g, void* l) {
  __builtin_amdgcn_global_load_lds((__attribute__((address_space(1))) void*)(g),
                                   (__attribute__((address_space(3))) void*)(l), 16, 0, 0);
}

// ---------------- fp32 -> f16 convert ----------------
__global__ __launch_bounds__(256) void conv_f16(const float* __restrict__ src,
                                                _Float16* __restrict__ dst, int n) {
  int i = (blockIdx.x * 256 + threadIdx.x) * 4;
  if (i + 3 < n) {
    float4 v = *reinterpret_cast<const float4*>(src + i);
    dst[i + 0] = (_Float16)v.x;
    dst[i + 1] = (_Float16)v.y;
    dst[i + 2] = (_Float16)v.z;
    dst[i + 3] = (_Float16)v.w;
  }
}

// ---------------- tiled transpose fp32[R][C] -> f16[C][R] ----------------
__global__ __launch_bounds__(256) void transpose_f16(const float* __restrict__ src,
                                                     _Float16* __restrict__ dst,
                                                     int R, int C) {
  __shared__ float tile[32][33];
  int c0 = blockIdx.x * 32, r0 = blockIdx.y * 32;
  int x = threadIdx.x & 31, y = threadIdx.x >> 5;
#pragma unroll
  for (int j = 0; j < 4; ++j)
    tile[y + j * 8][x] = src[(long)(r0 + y + j * 8) * C + c0 + x];
  __syncthreads();
#pragma unroll
  for (int j = 0; j < 4; ++j)
    dst[(long)(c0 + y + j * 8) * R + r0 + x] = (_Float16)tile[x][y + j * 8];
}

// ---------------- GEMM: C[M][N] = A[M][K] * BT[N][K]^T ----------------
// 128x128 tile, BK=64, DOUBLE-BUFFERED global_load_lds staging (T3-minimum:
// issue stage(t+1) before compute(t), one barrier per tile), XCD swizzle.
template <bool OUTF32>
__global__ __launch_bounds__(256) void gemm_bt(const _Float16* __restrict__ A, int lda,
                                               const _Float16* __restrict__ BT, int ldb,
                                               void* __restrict__ Cv, int ldc, int K) {
  __shared__ alignas(16) char As[2][128 * 128];
  __shared__ alignas(16) char Bs[2][128 * 128];
  const int tid = threadIdx.x;
  const int lane = tid & 63;
  const int wave = tid >> 6;
  const int wm = wave >> 1, wn = wave & 1;
  const int nwg = (int)(gridDim.x * gridDim.y);
  const int bid = (int)(blockIdx.y * gridDim.x + blockIdx.x);
  const int swz = (bid & 7) * (nwg >> 3) + (bid >> 3);
  const int m0 = (swz / (int)gridDim.x) * 128, n0 = (swz % (int)gridDim.x) * 128;
  f32x4 acc[4][4] = {};
  int srow[4], scs[4];
#pragma unroll
  for (int j = 0; j < 4; ++j) {
    int i = j * 256 + tid;
    srow[j] = i >> 3;
    scs[j] = (i & 7) ^ (srow[j] & 7);  // inverse-swizzled source chunk
  }
  auto stage = [&](int k0, int buf) {
#pragma unroll
    for (int j = 0; j < 4; ++j)
      gload16(A + (long)(m0 + srow[j]) * lda + k0 + scs[j] * 8, As[buf] + (j * 256 + tid) * 16);
#pragma unroll
    for (int j = 0; j < 4; ++j)
      gload16(BT + (long)(n0 + srow[j]) * ldb + k0 + scs[j] * 8, Bs[buf] + (j * 256 + tid) * 16);
  };

  stage(0, 0);
  __syncthreads();  // vmcnt drained at barrier -> buf0 ready
  const int nk = K >> 6;
  for (int t = 0; t < nk; ++t) {
    const int buf = t & 1;
    if (t + 1 < nk) stage((t + 1) << 6, buf ^ 1);  // async into other buffer
#pragma unroll
    for (int kk = 0; kk < 2; ++kk) {
      half8 af[4], bf[4];
#pragma unroll
      for (int mi = 0; mi < 4; ++mi) {
        int row = wm * 64 + mi * 16 + (lane & 15);
        int b = (row * 128 + kk * 64 + ((lane >> 4) * 16)) ^ ((row & 7) << 4);
        af[mi] = *reinterpret_cast<const half8*>(As[buf] + b);
      }
#pragma unroll
      for (int ni = 0; ni < 4; ++ni) {
        int row = wn * 64 + ni * 16 + (lane & 15);
        int b = (row * 128 + kk * 64 + ((lane >> 4) * 16)) ^ ((row & 7) << 4);
        bf[ni] = *reinterpret_cast<const half8*>(Bs[buf] + b);
      }
#pragma unroll
      for (int mi = 0; mi < 4; ++mi)
#pragma unroll
        for (int ni = 0; ni < 4; ++ni)
          acc[mi][ni] =
              __builtin_amdgcn_mfma_f32_16x16x32_f16(af[mi], bf[ni], acc[mi][ni], 0, 0, 0);
    }
    __syncthreads();  // compute(buf) done everywhere + stage(buf^1) drained
  }
#pragma unroll
  for (int mi = 0; mi < 4; ++mi) {
#pragma unroll
    for (int ni = 0; ni < 4; ++ni) {
      int row = m0 + wm * 64 + mi * 16 + ((lane >> 4) << 2);
      int col = n0 + wn * 64 + ni * 16 + (lane & 15);
      f32x4 v = acc[mi][ni];
#pragma unroll
      for (int r = 0; r < 4; ++r) {
        if constexpr (OUTF32)
          reinterpret_cast<float*>(Cv)[(long)(row + r) * ldc + col] = v[r];
        else
          reinterpret_cast<_Float16*>(Cv)[(long)(row + r) * ldc + col] = (_Float16)v[r];
      }
    }
  }
}

// ---------------- RoPE in-place on q and k ----------------
__global__ __launch_bounds__(256) void rope_k(_Float16* __restrict__ q,
                                              _Float16* __restrict__ k) {
  int idx = blockIdx.x * 256 + threadIdx.x;
  _Float16* p = (idx & (1 << 22)) ? k : q;
  int rem = idx & ((1 << 22) - 1);
  int row = rem >> 10;
  int pr = rem & 1023;
  int hh = pr >> 6, dp = pr & 63;
  int s = row & 2047;
  float invf = exp2f(-(float)dp * (13.287712379549449f / 64.0f));
  float f = (float)s * invf;
  float cs = cosf(f), sn = sinf(f);
  long base = (long)row * 2048 + hh * 128 + dp;
  float x1 = (float)p[base], x2 = (float)p[base + 64];
  p[base] = (_Float16)(x1 * cs - x2 * sn);
  p[base + 64] = (_Float16)(x2 * cs + x1 * sn);
}

// ---------------- fused causal flash attention (v5: folded) ----------------
// Block bx processes q-tiles {bx, 15-bx} (128 rows each) sequentially ->
// nt sums to 34 KV-tiles for EVERY block; grid (8,16,2)=256 equal blocks.
// 4 waves x 32 q (2 groups of 16); KV tiles of 64, double-buffered,
// global_load_lds staging; swapped QK^T; in-register softmax; defer-max.
__global__ __launch_bounds__(256) void attn_fused(const _Float16* __restrict__ Q,
                                                  const _Float16* __restrict__ Kr,
                                                  const _Float16* __restrict__ VT,
                                                  _Float16* __restrict__ O) {
  __shared__ alignas(16) char Ks[2][64 * 256];    // [key][chunk^(key&7)]
  __shared__ alignas(16) char Vs[2][128 * 128];   // [d][chunk^(d&7)] of VT tile
  const int tid = threadIdx.x, lane = tid & 63, wave = tid >> 6;
  const int g = lane >> 4;
  const int bx = (int)blockIdx.x;  // 0..7
  const int h = blockIdx.y, b = blockIdx.z;
  const long sbase = (long)b * 2048;
  const int colbase = h * 128;

  int k_kr[4], k_cs[4], v_vr[4], v_cs[4];
#pragma unroll
  for (int j = 0; j < 4; ++j) {
    int ci = j * 256 + tid;
    k_kr[j] = ci >> 4;
    k_cs[j] = (ci & 15) ^ (k_kr[j] & 7);
    v_vr[j] = ci >> 3;
    v_cs[j] = (ci & 7) ^ (v_vr[j] & 7);
  }
  auto stage = [&](int k0, int buf) {
#pragma unroll
    for (int j = 0; j < 4; ++j)
      gload16(Kr + (sbase + k0 + k_kr[j]) * 2048 + colbase + k_cs[j] * 8,
              Ks[buf] + (j * 256 + tid) * 16);
#pragma unroll
    for (int j = 0; j < 4; ++j)
      gload16(VT + (long)(colbase + v_vr[j]) * 4096 + sbase + k0 + v_cs[j] * 8,
              Vs[buf] + (j * 256 + tid) * 16);
  };

  for (int half = 0; half < 2; ++half) {
    const int qt = half ? 15 - bx : bx;
    const int q0 = qt * 128;
    const int qa_own = q0 + wave * 32 + (lane & 15);
    const int qb_own = qa_own + 16;

    half8 qfa[4], qfb[4];
    {
      const _Float16 hs = (_Float16)0.08838834764831845f;
      const _Float16* qpa = Q + (sbase + qa_own) * 2048 + colbase + g * 8;
      const _Float16* qpb = Q + (sbase + qb_own) * 2048 + colbase + g * 8;
#pragma unroll
      for (int c = 0; c < 4; ++c) {
        qfa[c] = (*reinterpret_cast<const half8*>(qpa + c * 32)) * hs;
        qfb[c] = (*reinterpret_cast<const half8*>(qpb + c * 32)) * hs;
      }
    }
    f32x4 oa[8] = {}, ob[8] = {};
    float ma = -INFINITY, la = 0.f, mb = -INFINITY, lb = 0.f;
    float mra[4] = {-INFINITY, -INFINITY, -INFINITY, -INFINITY};
    float mrb[4] = {-INFINITY, -INFINITY, -INFINITY, -INFINITY};
    const int nt = 2 * qt + 2;

    stage(0, 0);
    __syncthreads();

    for (int t = 0; t < nt; ++t) {
      const int cur = t & 1;
      const int k0 = t * 64;
      if (t + 1 < nt) stage(k0 + 64, cur ^ 1);

      const bool active = !(t == nt - 1 && wave < 2);
      if (active) {
        // ---- S^T = K Q^T for both q-groups (K-frag read once) ----
        f32x4 sa[4] = {}, sb[4] = {};
        __builtin_amdgcn_s_setprio(1);
#pragma unroll
        for (int n = 0; n < 4; ++n) {
          int key = n * 16 + (lane & 15);
#pragma unroll
          for (int c = 0; c < 4; ++c) {
            half8 kf = *reinterpret_cast<const half8*>(
                Ks[cur] + key * 256 + (((c * 4 + g) ^ (key & 7)) * 16));
            sa[n] = __builtin_amdgcn_mfma_f32_16x16x32_f16(kf, qfa[c], sa[n], 0, 0, 0);
            sb[n] = __builtin_amdgcn_mfma_f32_16x16x32_f16(kf, qfb[c], sb[n], 0, 0, 0);
          }
        }
        __builtin_amdgcn_s_setprio(0);

        // ---- causal mask (last two tiles of this half) ----
        if (t >= nt - 2) {
          int kba = k0 + g * 4 - qa_own;
          int kbb = kba - 16;
#pragma unroll
          for (int n = 0; n < 4; ++n)
#pragma unroll
            for (int r = 0; r < 4; ++r) {
              if (kba + n * 16 + r > 0) sa[n][r] = -INFINITY;
              if (kbb + n * 16 + r > 0) sb[n][r] = -INFINITY;
            }
        }

        // ---- online softmax, defer-max ----
        float mxa = fmaxf(fmaxf(fmaxf(sa[0][0], sa[0][1]), fmaxf(sa[0][2], sa[0][3])),
                          fmaxf(fmaxf(sa[1][0], sa[1][1]), fmaxf(sa[1][2], sa[1][3])));
        mxa = fmaxf(mxa, fmaxf(fmaxf(fmaxf(sa[2][0], sa[2][1]), fmaxf(sa[2][2], sa[2][3])),
                               fmaxf(fmaxf(sa[3][0], sa[3][1]), fmaxf(sa[3][2], sa[3][3]))));
        float mxb = fmaxf(fmaxf(fmaxf(sb[0][0], sb[0][1]), fmaxf(sb[0][2], sb[0][3])),
                          fmaxf(fmaxf(sb[1][0], sb[1][1]), fmaxf(sb[1][2], sb[1][3])));
        mxb = fmaxf(mxb, fmaxf(fmaxf(fmaxf(sb[2][0], sb[2][1]), fmaxf(sb[2][2], sb[2][3])),
                               fmaxf(fmaxf(sb[3][0], sb[3][1]), fmaxf(sb[3][2], sb[3][3]))));
        mxa = fmaxf(mxa, __shfl_xor(mxa, 16));
        mxa = fmaxf(mxa, __shfl_xor(mxa, 32));
        mxb = fmaxf(mxb, __shfl_xor(mxb, 16));
        mxb = fmaxf(mxb, __shfl_xor(mxb, 32));

        bool need = (mxa > ma + 8.f) || (mxb > mb + 8.f);
        if (__any(need)) {
          float mna = fmaxf(ma, mxa), mnb = fmaxf(mb, mxb);
          float alfa[4], alfb[4];
#pragma unroll
          for (int r = 0; r < 4; ++r) {
            float va = __shfl(mna, (lane & 48) | (g * 4 + r));
            alfa[r] = __expf(mra[r] - va);
            mra[r] = va;
            float vb = __shfl(mnb, (lane & 48) | (g * 4 + r));
            alfb[r] = __expf(mrb[r] - vb);
            mrb[r] = vb;
          }
          la *= __expf(ma - mna);
          lb *= __expf(mb - mnb);
          ma = mna;
          mb = mnb;
#pragma unroll
          for (int n = 0; n < 8; ++n) {
            f32x4 ta = oa[n], tb = ob[n];
            ta[0] *= alfa[0]; ta[1] *= alfa[1]; ta[2] *= alfa[2]; ta[3] *= alfa[3];
            tb[0] *= alfb[0]; tb[1] *= alfb[1]; tb[2] *= alfb[2]; tb[3] *= alfb[3];
            oa[n] = ta; ob[n] = tb;
          }
        }

        float pea[4][4], peb[4][4];
#pragma unroll
        for (int n = 0; n < 4; ++n)
#pragma unroll
          for (int r = 0; r < 4; ++r) {
            pea[n][r] = __expf(sa[n][r] - ma);
            peb[n][r] = __expf(sb[n][r] - mb);
          }
        {
          float lsa = 0.f, lsb = 0.f;
#pragma unroll
          for (int n = 0; n < 4; ++n)
#pragma unroll
            for (int r = 0; r < 4; ++r) { lsa += pea[n][r]; lsb += peb[n][r]; }
          lsa += __shfl_xor(lsa, 16);
          lsa += __shfl_xor(lsa, 32);
          lsb += __shfl_xor(lsb, 16);
          lsb += __shfl_xor(lsb, 32);
          la += lsa;
          lb += lsb;
        }

        // ---- pack P to f16 PV A-fragments via permlane swaps ----
        half8 paa[2], pab[2];
        {
          unsigned loa[4], hia[4], lob[4], hib[4];
#pragma unroll
          for (int n = 0; n < 4; ++n) {
            loa[n] = __builtin_bit_cast(unsigned, __builtin_amdgcn_cvt_pkrtz(pea[n][0], pea[n][1]));
            hia[n] = __builtin_bit_cast(unsigned, __builtin_amdgcn_cvt_pkrtz(pea[n][2], pea[n][3]));
            lob[n] = __builtin_bit_cast(unsigned, __builtin_amdgcn_cvt_pkrtz(peb[n][0], peb[n][1]));
            hib[n] = __builtin_bit_cast(unsigned, __builtin_amdgcn_cvt_pkrtz(peb[n][2], peb[n][3]));
          }
#pragma unroll
          for (int ks = 0; ks < 2; ++ks) {
            unsigned al = loa[ks * 2], bl = loa[ks * 2 + 1];
            unsigned ah = hia[ks * 2], bh = hia[ks * 2 + 1];
            asm("v_permlane32_swap_b32 %0, %1" : "+v"(al), "+v"(bl));
            asm("v_permlane16_swap_b32 %0, %1" : "+v"(al), "+v"(bl));
            asm("v_permlane32_swap_b32 %0, %1" : "+v"(ah), "+v"(bh));
            asm("v_permlane16_swap_b32 %0, %1" : "+v"(ah), "+v"(bh));
            u32x4 w; w[0] = al; w[1] = ah; w[2] = bl; w[3] = bh;
            paa[ks] = __builtin_bit_cast(half8, w);
            unsigned al2 = lob[ks * 2], bl2 = lob[ks * 2 + 1];
            unsigned ah2 = hib[ks * 2], bh2 = hib[ks * 2 + 1];
            asm("v_permlane32_swap_b32 %0, %1" : "+v"(al2), "+v"(bl2));
            asm("v_permlane16_swap_b32 %0, %1" : "+v"(al2), "+v"(bl2));
            asm("v_permlane32_swap_b32 %0, %1" : "+v"(ah2), "+v"(bh2));
            asm("v_permlane16_swap_b32 %0, %1" : "+v"(ah2), "+v"(bh2));
            u32x4 w2; w2[0] = al2; w2[1] = ah2; w2[2] = bl2; w2[3] = bh2;
            pab[ks] = __builtin_bit_cast(half8, w2);
          }
        }

        // ---- O += P V (V-frag read once, feeds both groups) ----
        __builtin_amdgcn_s_setprio(1);
#pragma unroll
        for (int n = 0; n < 8; ++n) {
          int d = n * 16 + (lane & 15);
#pragma unroll
          for (int ks = 0; ks < 2; ++ks) {
            half8 vf = *reinterpret_cast<const half8*>(
                Vs[cur] + d * 128 + (((ks * 4 + g) ^ (d & 7)) * 16));
            oa[n] = __builtin_amdgcn_mfma_f32_16x16x32_f16(paa[ks], vf, oa[n], 0, 0, 0);
            ob[n] = __builtin_amdgcn_mfma_f32_16x16x32_f16(pab[ks], vf, ob[n], 0, 0, 0);
          }
        }
        __builtin_amdgcn_s_setprio(0);
      }
      __syncthreads();  // compute(cur) done everywhere + stage(next) drained
    }

    // ---- epilogue for this half ----
    float lra[4], lrb[4];
#pragma unroll
    for (int r = 0; r < 4; ++r) {
      lra[r] = __shfl(la, (lane & 48) | (g * 4 + r));
      lrb[r] = __shfl(lb, (lane & 48) | (g * 4 + r));
    }
#pragma unroll
    for (int n = 0; n < 8; ++n) {
      int d = colbase + n * 16 + (lane & 15);
#pragma unroll
      for (int r = 0; r < 4; ++r) {
        int rowa = q0 + wave * 32 + (g << 2) + r;
        O[(sbase + rowa) * 2048 + d] = (_Float16)(oa[n][r] / lra[r]);
        O[(sbase + rowa + 16) * 2048 + d] = (_Float16)(ob[n][r] / lrb[r]);
      }
    }
  }
}

extern "C" void kernel_launch(void* const* d_in, const int* in_sizes, int n_in,
                              void* d_out, int out_size, void* d_ws, size_t ws_size,
                              hipStream_t stream) {
  const float* x     = (const float*)d_in[0];
  const float* Wq_d  = (const float*)d_in[1];
  const float* Wkv_d = (const float*)d_in[2];
  const float* Wq_u  = (const float*)d_in[3];
  const float* Wk_u  = (const float*)d_in[4];
  const float* Wv_u  = (const float*)d_in[5];
  const float* Wo    = (const float*)d_in[6];
  char* ws = (char*)d_ws;
  _Float16* xb  = (_Float16*)(ws);              // [4096][2048] (reused as ao)
  _Float16* wdT = (_Float16*)(ws + 16777216);   // [1024][2048]
  _Float16* wuT = (_Float16*)(ws + 20971520);   // 3x [2048][512]
  _Float16* woT = (_Float16*)(ws + 27262976);   // [2048][2048]
  _Float16* lat = (_Float16*)(ws + 35651584);   // [4096][1024]
  _Float16* qb  = (_Float16*)(ws + 44040192);   // [4096][2048]
  _Float16* kb  = (_Float16*)(ws + 60817408);   // [4096][2048]
  _Float16* vT  = (_Float16*)(ws + 77594624);   // [2048 d][4096 s]
  _Float16* ao  = xb;

  conv_f16<<<8192, 256, 0, stream>>>(x, xb, 8388608);
  transpose_f16<<<dim3(16, 64), 256, 0, stream>>>(Wq_d, wdT, 2048, 512);
  transpose_f16<<<dim3(16, 64), 256, 0, stream>>>(Wkv_d, wdT + 512 * 2048, 2048, 512);
  transpose_f16<<<dim3(64, 16), 256, 0, stream>>>(Wq_u, wuT, 512, 2048);
  transpose_f16<<<dim3(64, 16), 256, 0, stream>>>(Wk_u, wuT + 2048 * 512, 512, 2048);
  transpose_f16<<<dim3(64, 16), 256, 0, stream>>>(Wv_u, wuT + 2 * 2048 * 512, 512, 2048);
  transpose_f16<<<dim3(64, 64), 256, 0, stream>>>(Wo, woT, 2048, 2048);

  // lat = x @ [Wq_d | Wkv_d]
  gemm_bt<false><<<dim3(8, 32), 256, 0, stream>>>(xb, 2048, wdT, 2048, lat, 1024, 2048);
  // q = lat_q @ Wq_u ; k = lat_kv @ Wk_u   (row-major outputs)
  gemm_bt<false><<<dim3(16, 32), 256, 0, stream>>>(lat, 1024, wuT, 512, qb, 2048, 512);
  gemm_bt<false><<<dim3(16, 32), 256, 0, stream>>>(lat + 512, 1024, wuT + 2048 * 512, 512, kb, 2048, 512);
  // vT[d][s] = Wv_u^T @ lat_kv^T  (transposed output, same FLOPs)
  gemm_bt<false><<<dim3(32, 16), 256, 0, stream>>>(wuT + 2 * 2048 * 512, 512, lat + 512, 1024, vT, 4096, 512);

  rope_k<<<32768, 256, 0, stream>>>(qb, kb);
  attn_fused<<<dim3(8, 16, 2), 256, 0, stream>>>(qb, kb, vT, ao);

  gemm_bt<true><<<dim3(16, 32), 256, 0, stream>>>(ao, 2048, woT, 2048, d_out, 2048, 2048);
}

// Round 7
// 242.961 us; speedup vs baseline: 2.6713x; 1.0420x over previous
//
#include <hip/hip_runtime.h>
#include <hip/hip_bf16.h>
#include <cstdint>

typedef _Float16 half8 __attribute__((ext_vector_type(8)));
typedef float f32x4 __attribute__((ext_vector_type(4)));
typedef unsigned u32x4 __attribute__((ext_vector_type(4)));

__device__ __forceinline__ void gload16(const void* g, void* l) {
  __builtin_amdgcn_global_load_lds((__attribute__((address_space(1))) void*)(g),
                                   (__attribute__((address_space(3))) void*)(l), 16, 0, 0);
}

// ---------------- fp32 -> f16 convert ----------------
__global__ __launch_bounds__(256) void conv_f16(const float* __restrict__ src,
                                                _Float16* __restrict__ dst, int n) {
  int i = (blockIdx.x * 256 + threadIdx.x) * 4;
  if (i + 3 < n) {
    float4 v = *reinterpret_cast<const float4*>(src + i);
    dst[i + 0] = (_Float16)v.x;
    dst[i + 1] = (_Float16)v.y;
    dst[i + 2] = (_Float16)v.z;
    dst[i + 3] = (_Float16)v.w;
  }
}

// ---------------- tiled transpose fp32[R][C] -> f16[C][R] ----------------
__global__ __launch_bounds__(256) void transpose_f16(const float* __restrict__ src,
                                                     _Float16* __restrict__ dst,
                                                     int R, int C) {
  __shared__ float tile[32][33];
  int c0 = blockIdx.x * 32, r0 = blockIdx.y * 32;
  int x = threadIdx.x & 31, y = threadIdx.x >> 5;
#pragma unroll
  for (int j = 0; j < 4; ++j)
    tile[y + j * 8][x] = src[(long)(r0 + y + j * 8) * C + c0 + x];
  __syncthreads();
#pragma unroll
  for (int j = 0; j < 4; ++j)
    dst[(long)(c0 + y + j * 8) * R + r0 + x] = (_Float16)tile[x][y + j * 8];
}

// ---------------- GEMM: C[M][N] = A[M][K] * BT[N][K]^T ----------------
// 128x128 tile, BK=64, double-buffered global_load_lds staging, XCD swizzle.
template <bool OUTF32>
__global__ __launch_bounds__(256) void gemm_bt(const _Float16* __restrict__ A, int lda,
                                               const _Float16* __restrict__ BT, int ldb,
                                               void* __restrict__ Cv, int ldc, int K) {
  __shared__ alignas(16) char As[2][128 * 128];
  __shared__ alignas(16) char Bs[2][128 * 128];
  const int tid = threadIdx.x;
  const int lane = tid & 63;
  const int wave = tid >> 6;
  const int wm = wave >> 1, wn = wave & 1;
  const int nwg = (int)(gridDim.x * gridDim.y);
  const int bid = (int)(blockIdx.y * gridDim.x + blockIdx.x);
  const int swz = (bid & 7) * (nwg >> 3) + (bid >> 3);
  const int m0 = (swz / (int)gridDim.x) * 128, n0 = (swz % (int)gridDim.x) * 128;
  f32x4 acc[4][4] = {};
  int srow[4], scs[4];
#pragma unroll
  for (int j = 0; j < 4; ++j) {
    int i = j * 256 + tid;
    srow[j] = i >> 3;
    scs[j] = (i & 7) ^ (srow[j] & 7);
  }
  auto stage = [&](int k0, int buf) {
#pragma unroll
    for (int j = 0; j < 4; ++j)
      gload16(A + (long)(m0 + srow[j]) * lda + k0 + scs[j] * 8, As[buf] + (j * 256 + tid) * 16);
#pragma unroll
    for (int j = 0; j < 4; ++j)
      gload16(BT + (long)(n0 + srow[j]) * ldb + k0 + scs[j] * 8, Bs[buf] + (j * 256 + tid) * 16);
  };

  stage(0, 0);
  __syncthreads();
  const int nk = K >> 6;
  for (int t = 0; t < nk; ++t) {
    const int buf = t & 1;
    if (t + 1 < nk) stage((t + 1) << 6, buf ^ 1);
#pragma unroll
    for (int kk = 0; kk < 2; ++kk) {
      half8 af[4], bf[4];
#pragma unroll
      for (int mi = 0; mi < 4; ++mi) {
        int row = wm * 64 + mi * 16 + (lane & 15);
        int b = (row * 128 + kk * 64 + ((lane >> 4) * 16)) ^ ((row & 7) << 4);
        af[mi] = *reinterpret_cast<const half8*>(As[buf] + b);
      }
#pragma unroll
      for (int ni = 0; ni < 4; ++ni) {
        int row = wn * 64 + ni * 16 + (lane & 15);
        int b = (row * 128 + kk * 64 + ((lane >> 4) * 16)) ^ ((row & 7) << 4);
        bf[ni] = *reinterpret_cast<const half8*>(Bs[buf] + b);
      }
#pragma unroll
      for (int mi = 0; mi < 4; ++mi)
#pragma unroll
        for (int ni = 0; ni < 4; ++ni)
          acc[mi][ni] =
              __builtin_amdgcn_mfma_f32_16x16x32_f16(af[mi], bf[ni], acc[mi][ni], 0, 0, 0);
    }
    __syncthreads();
  }
#pragma unroll
  for (int mi = 0; mi < 4; ++mi) {
#pragma unroll
    for (int ni = 0; ni < 4; ++ni) {
      int row = m0 + wm * 64 + mi * 16 + ((lane >> 4) << 2);
      int col = n0 + wn * 64 + ni * 16 + (lane & 15);
      f32x4 v = acc[mi][ni];
#pragma unroll
      for (int r = 0; r < 4; ++r) {
        if constexpr (OUTF32)
          reinterpret_cast<float*>(Cv)[(long)(row + r) * ldc + col] = v[r];
        else
          reinterpret_cast<_Float16*>(Cv)[(long)(row + r) * ldc + col] = (_Float16)v[r];
      }
    }
  }
}

// ---------------- RoPE in-place on q and k ----------------
__global__ __launch_bounds__(256) void rope_k(_Float16* __restrict__ q,
                                              _Float16* __restrict__ k) {
  int idx = blockIdx.x * 256 + threadIdx.x;
  _Float16* p = (idx & (1 << 22)) ? k : q;
  int rem = idx & ((1 << 22) - 1);
  int row = rem >> 10;
  int pr = rem & 1023;
  int hh = pr >> 6, dp = pr & 63;
  int s = row & 2047;
  float invf = exp2f(-(float)dp * (13.287712379549449f / 64.0f));
  float f = (float)s * invf;
  float cs = cosf(f), sn = sinf(f);
  long base = (long)row * 2048 + hh * 128 + dp;
  float x1 = (float)p[base], x2 = (float)p[base + 64];
  p[base] = (_Float16)(x1 * cs - x2 * sn);
  p[base + 64] = (_Float16)(x2 * cs + x1 * sn);
}

// ---------------- fused causal flash attention (v4 + XCD-clustered remap) ----------------
// EXACT r4 math/structure (last known good). Only the block-index derivation changed:
// flat -> (xcd, slot); qt = 15-(slot&15) (longest first); hb = (slot>>4)*8 + xcd.
// Under bid%8 XCD round-robin this pins all 16 q-tiles of an (h,b) to one XCD's L2.
__global__ __launch_bounds__(256, 2) void attn_fused(const _Float16* __restrict__ Q,
                                                     const _Float16* __restrict__ Kr,
                                                     const _Float16* __restrict__ VT,
                                                     _Float16* __restrict__ O) {
  __shared__ alignas(16) char Ks[2][64 * 256];    // [key][chunk^(key&7)]
  __shared__ alignas(16) char Vs[2][128 * 128];   // [d][chunk^(d&7)] of VT tile
  const int tid = threadIdx.x, lane = tid & 63, wave = tid >> 6;
  const int g = lane >> 4;
  const int flat = (int)(blockIdx.x + 16 * blockIdx.y + 256 * blockIdx.z);  // 0..511
  const int xcd = flat & 7;
  const int slot = flat >> 3;                 // 0..63
  const int qt = 15 - (slot & 15);            // longest blocks first within XCD
  const int hb = (slot >> 4) * 8 + xcd;       // 4 (h,b) pairs per XCD
  const int h = hb & 15, b = hb >> 4;
  const long sbase = (long)b * 2048;
  const int q0 = qt * 128;
  const int colbase = h * 128;
  const int qa_own = q0 + wave * 32 + (lane & 15);
  const int qb_own = qa_own + 16;

  half8 qfa[4], qfb[4];
  {
    const _Float16 hs = (_Float16)0.08838834764831845f;
    const _Float16* qpa = Q + (sbase + qa_own) * 2048 + colbase + g * 8;
    const _Float16* qpb = Q + (sbase + qb_own) * 2048 + colbase + g * 8;
#pragma unroll
    for (int c = 0; c < 4; ++c) {
      qfa[c] = (*reinterpret_cast<const half8*>(qpa + c * 32)) * hs;
      qfb[c] = (*reinterpret_cast<const half8*>(qpb + c * 32)) * hs;
    }
  }
  f32x4 oa[8] = {}, ob[8] = {};
  float ma = -INFINITY, la = 0.f, mb = -INFINITY, lb = 0.f;
  float mra[4] = {-INFINITY, -INFINITY, -INFINITY, -INFINITY};
  float mrb[4] = {-INFINITY, -INFINITY, -INFINITY, -INFINITY};
  const int nt = 2 * qt + 2;

  int k_kr[4], k_cs[4], v_vr[4], v_cs[4];
#pragma unroll
  for (int j = 0; j < 4; ++j) {
    int ci = j * 256 + tid;
    k_kr[j] = ci >> 4;
    k_cs[j] = (ci & 15) ^ (k_kr[j] & 7);
    v_vr[j] = ci >> 3;
    v_cs[j] = (ci & 7) ^ (v_vr[j] & 7);
  }
  auto stage = [&](int k0, int buf) {
#pragma unroll
    for (int j = 0; j < 4; ++j)
      gload16(Kr + (sbase + k0 + k_kr[j]) * 2048 + colbase + k_cs[j] * 8,
              Ks[buf] + (j * 256 + tid) * 16);
#pragma unroll
    for (int j = 0; j < 4; ++j)
      gload16(VT + (long)(colbase + v_vr[j]) * 4096 + sbase + k0 + v_cs[j] * 8,
              Vs[buf] + (j * 256 + tid) * 16);
  };

  stage(0, 0);
  __syncthreads();

  for (int t = 0; t < nt; ++t) {
    const int cur = t & 1;
    const int k0 = t * 64;
    if (t + 1 < nt) stage(k0 + 64, cur ^ 1);

    const bool active = !(t == nt - 1 && wave < 2);
    if (active) {
      // ---- S^T = K Q^T for both q-groups (K-frag read once) ----
      f32x4 sa[4] = {}, sb[4] = {};
      __builtin_amdgcn_s_setprio(1);
#pragma unroll
      for (int n = 0; n < 4; ++n) {
        int key = n * 16 + (lane & 15);
#pragma unroll
        for (int c = 0; c < 4; ++c) {
          half8 kf = *reinterpret_cast<const half8*>(
              Ks[cur] + key * 256 + (((c * 4 + g) ^ (key & 7)) * 16));
          sa[n] = __builtin_amdgcn_mfma_f32_16x16x32_f16(kf, qfa[c], sa[n], 0, 0, 0);
          sb[n] = __builtin_amdgcn_mfma_f32_16x16x32_f16(kf, qfb[c], sb[n], 0, 0, 0);
        }
      }
      __builtin_amdgcn_s_setprio(0);

      // ---- causal mask (last two tiles only) ----
      if (t >= nt - 2) {
        int kba = k0 + g * 4 - qa_own;
        int kbb = kba - 16;
#pragma unroll
        for (int n = 0; n < 4; ++n)
#pragma unroll
          for (int r = 0; r < 4; ++r) {
            if (kba + n * 16 + r > 0) sa[n][r] = -INFINITY;
            if (kbb + n * 16 + r > 0) sb[n][r] = -INFINITY;
          }
      }

      // ---- online softmax, defer-max ----
      float mxa = fmaxf(fmaxf(fmaxf(sa[0][0], sa[0][1]), fmaxf(sa[0][2], sa[0][3])),
                        fmaxf(fmaxf(sa[1][0], sa[1][1]), fmaxf(sa[1][2], sa[1][3])));
      mxa = fmaxf(mxa, fmaxf(fmaxf(fmaxf(sa[2][0], sa[2][1]), fmaxf(sa[2][2], sa[2][3])),
                             fmaxf(fmaxf(sa[3][0], sa[3][1]), fmaxf(sa[3][2], sa[3][3]))));
      float mxb = fmaxf(fmaxf(fmaxf(sb[0][0], sb[0][1]), fmaxf(sb[0][2], sb[0][3])),
                        fmaxf(fmaxf(sb[1][0], sb[1][1]), fmaxf(sb[1][2], sb[1][3])));
      mxb = fmaxf(mxb, fmaxf(fmaxf(fmaxf(sb[2][0], sb[2][1]), fmaxf(sb[2][2], sb[2][3])),
                             fmaxf(fmaxf(sb[3][0], sb[3][1]), fmaxf(sb[3][2], sb[3][3]))));
      mxa = fmaxf(mxa, __shfl_xor(mxa, 16));
      mxa = fmaxf(mxa, __shfl_xor(mxa, 32));
      mxb = fmaxf(mxb, __shfl_xor(mxb, 16));
      mxb = fmaxf(mxb, __shfl_xor(mxb, 32));

      bool need = (mxa > ma + 8.f) || (mxb > mb + 8.f);
      if (__any(need)) {
        float mna = fmaxf(ma, mxa), mnb = fmaxf(mb, mxb);
        float alfa[4], alfb[4];
#pragma unroll
        for (int r = 0; r < 4; ++r) {
          float va = __shfl(mna, (lane & 48) | (g * 4 + r));
          alfa[r] = __expf(mra[r] - va);
          mra[r] = va;
          float vb = __shfl(mnb, (lane & 48) | (g * 4 + r));
          alfb[r] = __expf(mrb[r] - vb);
          mrb[r] = vb;
        }
        la *= __expf(ma - mna);
        lb *= __expf(mb - mnb);
        ma = mna;
        mb = mnb;
#pragma unroll
        for (int n = 0; n < 8; ++n) {
          f32x4 ta = oa[n], tb = ob[n];
          ta[0] *= alfa[0]; ta[1] *= alfa[1]; ta[2] *= alfa[2]; ta[3] *= alfa[3];
          tb[0] *= alfb[0]; tb[1] *= alfb[1]; tb[2] *= alfb[2]; tb[3] *= alfb[3];
          oa[n] = ta; ob[n] = tb;
        }
      }

      float pea[4][4], peb[4][4];
#pragma unroll
      for (int n = 0; n < 4; ++n)
#pragma unroll
        for (int r = 0; r < 4; ++r) {
          pea[n][r] = __expf(sa[n][r] - ma);
          peb[n][r] = __expf(sb[n][r] - mb);
        }
      {
        float lsa = 0.f, lsb = 0.f;
#pragma unroll
        for (int n = 0; n < 4; ++n)
#pragma unroll
          for (int r = 0; r < 4; ++r) { lsa += pea[n][r]; lsb += peb[n][r]; }
        lsa += __shfl_xor(lsa, 16);
        lsa += __shfl_xor(lsa, 32);
        lsb += __shfl_xor(lsb, 16);
        lsb += __shfl_xor(lsb, 32);
        la += lsa;
        lb += lsb;
      }

      // ---- pack P to f16 PV A-fragments via permlane swaps ----
      half8 paa[2], pab[2];
      {
        unsigned loa[4], hia[4], lob[4], hib[4];
#pragma unroll
        for (int n = 0; n < 4; ++n) {
          loa[n] = __builtin_bit_cast(unsigned, __builtin_amdgcn_cvt_pkrtz(pea[n][0], pea[n][1]));
          hia[n] = __builtin_bit_cast(unsigned, __builtin_amdgcn_cvt_pkrtz(pea[n][2], pea[n][3]));
          lob[n] = __builtin_bit_cast(unsigned, __builtin_amdgcn_cvt_pkrtz(peb[n][0], peb[n][1]));
          hib[n] = __builtin_bit_cast(unsigned, __builtin_amdgcn_cvt_pkrtz(peb[n][2], peb[n][3]));
        }
#pragma unroll
        for (int ks = 0; ks < 2; ++ks) {
          unsigned al = loa[ks * 2], bl = loa[ks * 2 + 1];
          unsigned ah = hia[ks * 2], bh = hia[ks * 2 + 1];
          asm("v_permlane32_swap_b32 %0, %1" : "+v"(al), "+v"(bl));
          asm("v_permlane16_swap_b32 %0, %1" : "+v"(al), "+v"(bl));
          asm("v_permlane32_swap_b32 %0, %1" : "+v"(ah), "+v"(bh));
          asm("v_permlane16_swap_b32 %0, %1" : "+v"(ah), "+v"(bh));
          u32x4 w; w[0] = al; w[1] = ah; w[2] = bl; w[3] = bh;
          paa[ks] = __builtin_bit_cast(half8, w);
          unsigned al2 = lob[ks * 2], bl2 = lob[ks * 2 + 1];
          unsigned ah2 = hib[ks * 2], bh2 = hib[ks * 2 + 1];
          asm("v_permlane32_swap_b32 %0, %1" : "+v"(al2), "+v"(bl2));
          asm("v_permlane16_swap_b32 %0, %1" : "+v"(al2), "+v"(bl2));
          asm("v_permlane32_swap_b32 %0, %1" : "+v"(ah2), "+v"(bh2));
          asm("v_permlane16_swap_b32 %0, %1" : "+v"(ah2), "+v"(bh2));
          u32x4 w2; w2[0] = al2; w2[1] = ah2; w2[2] = bl2; w2[3] = bh2;
          pab[ks] = __builtin_bit_cast(half8, w2);
        }
      }

      // ---- O += P V (V-frag read once, feeds both groups) ----
      __builtin_amdgcn_s_setprio(1);
#pragma unroll
      for (int n = 0; n < 8; ++n) {
        int d = n * 16 + (lane & 15);
#pragma unroll
        for (int ks = 0; ks < 2; ++ks) {
          half8 vf = *reinterpret_cast<const half8*>(
              Vs[cur] + d * 128 + (((ks * 4 + g) ^ (d & 7)) * 16));
          oa[n] = __builtin_amdgcn_mfma_f32_16x16x32_f16(paa[ks], vf, oa[n], 0, 0, 0);
          ob[n] = __builtin_amdgcn_mfma_f32_16x16x32_f16(pab[ks], vf, ob[n], 0, 0, 0);
        }
      }
      __builtin_amdgcn_s_setprio(0);
    }
    __syncthreads();  // compute(cur) done everywhere + stage(next) drained
  }

  // ---- epilogue ----
  float lra[4], lrb[4];
#pragma unroll
  for (int r = 0; r < 4; ++r) {
    lra[r] = __shfl(la, (lane & 48) | (g * 4 + r));
    lrb[r] = __shfl(lb, (lane & 48) | (g * 4 + r));
  }
#pragma unroll
  for (int n = 0; n < 8; ++n) {
    int d = colbase + n * 16 + (lane & 15);
#pragma unroll
    for (int r = 0; r < 4; ++r) {
      int rowa = q0 + wave * 32 + (g << 2) + r;
      O[(sbase + rowa) * 2048 + d] = (_Float16)(oa[n][r] / lra[r]);
      O[(sbase + rowa + 16) * 2048 + d] = (_Float16)(ob[n][r] / lrb[r]);
    }
  }
}

extern "C" void kernel_launch(void* const* d_in, const int* in_sizes, int n_in,
                              void* d_out, int out_size, void* d_ws, size_t ws_size,
                              hipStream_t stream) {
  const float* x     = (const float*)d_in[0];
  const float* Wq_d  = (const float*)d_in[1];
  const float* Wkv_d = (const float*)d_in[2];
  const float* Wq_u  = (const float*)d_in[3];
  const float* Wk_u  = (const float*)d_in[4];
  const float* Wv_u  = (const float*)d_in[5];
  const float* Wo    = (const float*)d_in[6];
  char* ws = (char*)d_ws;
  _Float16* xb  = (_Float16*)(ws);              // [4096][2048] (reused as ao)
  _Float16* wdT = (_Float16*)(ws + 16777216);   // [1024][2048]
  _Float16* wuT = (_Float16*)(ws + 20971520);   // 3x [2048][512]
  _Float16* woT = (_Float16*)(ws + 27262976);   // [2048][2048]
  _Float16* lat = (_Float16*)(ws + 35651584);   // [4096][1024]
  _Float16* qb  = (_Float16*)(ws + 44040192);   // [4096][2048]
  _Float16* kb  = (_Float16*)(ws + 60817408);   // [4096][2048]
  _Float16* vT  = (_Float16*)(ws + 77594624);   // [2048 d][4096 s]
  _Float16* ao  = xb;

  conv_f16<<<8192, 256, 0, stream>>>(x, xb, 8388608);
  transpose_f16<<<dim3(16, 64), 256, 0, stream>>>(Wq_d, wdT, 2048, 512);
  transpose_f16<<<dim3(16, 64), 256, 0, stream>>>(Wkv_d, wdT + 512 * 2048, 2048, 512);
  transpose_f16<<<dim3(64, 16), 256, 0, stream>>>(Wq_u, wuT, 512, 2048);
  transpose_f16<<<dim3(64, 16), 256, 0, stream>>>(Wk_u, wuT + 2048 * 512, 512, 2048);
  transpose_f16<<<dim3(64, 16), 256, 0, stream>>>(Wv_u, wuT + 2 * 2048 * 512, 512, 2048);
  transpose_f16<<<dim3(64, 64), 256, 0, stream>>>(Wo, woT, 2048, 2048);

  // lat = x @ [Wq_d | Wkv_d]
  gemm_bt<false><<<dim3(8, 32), 256, 0, stream>>>(xb, 2048, wdT, 2048, lat, 1024, 2048);
  // q = lat_q @ Wq_u ; k = lat_kv @ Wk_u   (row-major outputs)
  gemm_bt<false><<<dim3(16, 32), 256, 0, stream>>>(lat, 1024, wuT, 512, qb, 2048, 512);
  gemm_bt<false><<<dim3(16, 32), 256, 0, stream>>>(lat + 512, 1024, wuT + 2048 * 512, 512, kb, 2048, 512);
  // vT[d][s] = Wv_u^T @ lat_kv^T  (transposed output, same FLOPs)
  gemm_bt<false><<<dim3(32, 16), 256, 0, stream>>>(wuT + 2 * 2048 * 512, 512, lat + 512, 1024, vT, 4096, 512);

  rope_k<<<32768, 256, 0, stream>>>(qb, kb);
  attn_fused<<<dim3(16, 16, 2), 256, 0, stream>>>(qb, kb, vT, ao);

  gemm_bt<true><<<dim3(16, 32), 256, 0, stream>>>(ao, 2048, woT, 2048, d_out, 2048, 2048);
}

// Round 8
// 231.067 us; speedup vs baseline: 2.8088x; 1.0515x over previous
//
#include <hip/hip_runtime.h>
#include <hip/hip_bf16.h>
#include <cstdint>

typedef _Float16 half8 __attribute__((ext_vector_type(8)));
typedef float f32x4 __attribute__((ext_vector_type(4)));
typedef unsigned u32x4 __attribute__((ext_vector_type(4)));

__device__ __forceinline__ void gload16(const void* g, void* l) {
  __builtin_amdgcn_global_load_lds((__attribute__((address_space(1))) void*)(g),
                                   (__attribute__((address_space(3))) void*)(l), 16, 0, 0);
}

// ---------------- fp32 -> f16 convert ----------------
__global__ __launch_bounds__(256) void conv_f16(const float* __restrict__ src,
                                                _Float16* __restrict__ dst, int n) {
  int i = (blockIdx.x * 256 + threadIdx.x) * 4;
  if (i + 3 < n) {
    float4 v = *reinterpret_cast<const float4*>(src + i);
    dst[i + 0] = (_Float16)v.x;
    dst[i + 1] = (_Float16)v.y;
    dst[i + 2] = (_Float16)v.z;
    dst[i + 3] = (_Float16)v.w;
  }
}

// ---------------- tiled transpose fp32[R][C] -> f16[C][R] ----------------
__global__ __launch_bounds__(256) void transpose_f16(const float* __restrict__ src,
                                                     _Float16* __restrict__ dst,
                                                     int R, int C) {
  __shared__ float tile[32][33];
  int c0 = blockIdx.x * 32, r0 = blockIdx.y * 32;
  int x = threadIdx.x & 31, y = threadIdx.x >> 5;
#pragma unroll
  for (int j = 0; j < 4; ++j)
    tile[y + j * 8][x] = src[(long)(r0 + y + j * 8) * C + c0 + x];
  __syncthreads();
#pragma unroll
  for (int j = 0; j < 4; ++j)
    dst[(long)(c0 + y + j * 8) * R + r0 + x] = (_Float16)tile[x][y + j * 8];
}

// ---------------- GEMM: C[M][N] = A[M][K] * BT[N][K]^T ----------------
// 128x128 tile, BK=64, double-buffered global_load_lds staging, XCD swizzle.
template <bool OUTF32>
__global__ __launch_bounds__(256) void gemm_bt(const _Float16* __restrict__ A, int lda,
                                               const _Float16* __restrict__ BT, int ldb,
                                               void* __restrict__ Cv, int ldc, int K) {
  __shared__ alignas(16) char As[2][128 * 128];
  __shared__ alignas(16) char Bs[2][128 * 128];
  const int tid = threadIdx.x;
  const int lane = tid & 63;
  const int wave = tid >> 6;
  const int wm = wave >> 1, wn = wave & 1;
  const int nwg = (int)(gridDim.x * gridDim.y);
  const int bid = (int)(blockIdx.y * gridDim.x + blockIdx.x);
  const int swz = (bid & 7) * (nwg >> 3) + (bid >> 3);
  const int m0 = (swz / (int)gridDim.x) * 128, n0 = (swz % (int)gridDim.x) * 128;
  f32x4 acc[4][4] = {};
  int srow[4], scs[4];
#pragma unroll
  for (int j = 0; j < 4; ++j) {
    int i = j * 256 + tid;
    srow[j] = i >> 3;
    scs[j] = (i & 7) ^ (srow[j] & 7);
  }
  auto stage = [&](int k0, int buf) {
#pragma unroll
    for (int j = 0; j < 4; ++j)
      gload16(A + (long)(m0 + srow[j]) * lda + k0 + scs[j] * 8, As[buf] + (j * 256 + tid) * 16);
#pragma unroll
    for (int j = 0; j < 4; ++j)
      gload16(BT + (long)(n0 + srow[j]) * ldb + k0 + scs[j] * 8, Bs[buf] + (j * 256 + tid) * 16);
  };

  stage(0, 0);
  __syncthreads();
  const int nk = K >> 6;
  for (int t = 0; t < nk; ++t) {
    const int buf = t & 1;
    if (t + 1 < nk) stage((t + 1) << 6, buf ^ 1);
#pragma unroll
    for (int kk = 0; kk < 2; ++kk) {
      half8 af[4], bf[4];
#pragma unroll
      for (int mi = 0; mi < 4; ++mi) {
        int row = wm * 64 + mi * 16 + (lane & 15);
        int b = (row * 128 + kk * 64 + ((lane >> 4) * 16)) ^ ((row & 7) << 4);
        af[mi] = *reinterpret_cast<const half8*>(As[buf] + b);
      }
#pragma unroll
      for (int ni = 0; ni < 4; ++ni) {
        int row = wn * 64 + ni * 16 + (lane & 15);
        int b = (row * 128 + kk * 64 + ((lane >> 4) * 16)) ^ ((row & 7) << 4);
        bf[ni] = *reinterpret_cast<const half8*>(Bs[buf] + b);
      }
#pragma unroll
      for (int mi = 0; mi < 4; ++mi)
#pragma unroll
        for (int ni = 0; ni < 4; ++ni)
          acc[mi][ni] =
              __builtin_amdgcn_mfma_f32_16x16x32_f16(af[mi], bf[ni], acc[mi][ni], 0, 0, 0);
    }
    __syncthreads();
  }
#pragma unroll
  for (int mi = 0; mi < 4; ++mi) {
#pragma unroll
    for (int ni = 0; ni < 4; ++ni) {
      int row = m0 + wm * 64 + mi * 16 + ((lane >> 4) << 2);
      int col = n0 + wn * 64 + ni * 16 + (lane & 15);
      f32x4 v = acc[mi][ni];
#pragma unroll
      for (int r = 0; r < 4; ++r) {
        if constexpr (OUTF32)
          reinterpret_cast<float*>(Cv)[(long)(row + r) * ldc + col] = v[r];
        else
          reinterpret_cast<_Float16*>(Cv)[(long)(row + r) * ldc + col] = (_Float16)v[r];
      }
    }
  }
}

// ---------------- trig table: [2048 s][64 cos | 64 sin] fp32 ----------------
__global__ __launch_bounds__(256) void trig_tab(float* __restrict__ tab) {
  int idx = blockIdx.x * 256 + threadIdx.x;  // 2048*64
  int s = idx >> 6, dp = idx & 63;
  float invf = exp2f(-(float)dp * (13.287712379549449f / 64.0f));
  float f = (float)s * invf;
  float sn, cs;
  sincosf(f, &sn, &cs);
  tab[s * 128 + dp] = cs;
  tab[s * 128 + 64 + dp] = sn;
}

// ---------------- RoPE in-place on q and k (table lookup) ----------------
__global__ __launch_bounds__(256) void rope_k(_Float16* __restrict__ q,
                                              _Float16* __restrict__ k,
                                              const float* __restrict__ tab) {
  int idx = blockIdx.x * 256 + threadIdx.x;
  _Float16* p = (idx & (1 << 22)) ? k : q;
  int rem = idx & ((1 << 22) - 1);
  int row = rem >> 10;
  int pr = rem & 1023;
  int hh = pr >> 6, dp = pr & 63;
  int s = row & 2047;
  float cs = tab[s * 128 + dp], sn = tab[s * 128 + 64 + dp];
  long base = (long)row * 2048 + hh * 128 + dp;
  float x1 = (float)p[base], x2 = (float)p[base + 64];
  p[base] = (_Float16)(x1 * cs - x2 * sn);
  p[base + 64] = (_Float16)(x2 * cs + x1 * sn);
}

// ---------------- fused causal flash attention (v4 + complementary-pair remap) ----------------
// EXACT r7 math/structure. Only the block-index derivation changed:
// flat<256 (dispatched first, fills one slot per CU): qt = 15-(s&7)  (heavy)
// flat>=256 (second slot on the same CU):             qt = s&7       (light)
// -> every CU's two blocks total (2qt+2)+(2(15-qt)+2) = 34 tile-units (balanced),
// while keeping the r7 XCD clustering: hb = xcd + 8*(s>>3) (4 (h,b) per XCD's L2).
__global__ __launch_bounds__(256, 2) void attn_fused(const _Float16* __restrict__ Q,
                                                     const _Float16* __restrict__ Kr,
                                                     const _Float16* __restrict__ VT,
                                                     _Float16* __restrict__ O) {
  __shared__ alignas(16) char Ks[2][64 * 256];    // [key][chunk^(key&7)]
  __shared__ alignas(16) char Vs[2][128 * 128];   // [d][chunk^(d&7)] of VT tile
  const int tid = threadIdx.x, lane = tid & 63, wave = tid >> 6;
  const int g = lane >> 4;
  const int flat = (int)(blockIdx.x + 16 * blockIdx.y + 256 * blockIdx.z);  // 0..511
  const int round = flat >> 8;                // 0 = heavy (first), 1 = light
  const int r_ = flat & 255;
  const int xcd = r_ & 7;
  const int s_ = r_ >> 3;                     // 0..31 (CU slot within XCD)
  const int hb = xcd + 8 * (s_ >> 3);         // 4 (h,b) pairs per XCD
  const int qt = round ? (s_ & 7) : 15 - (s_ & 7);
  const int h = hb & 15, b = hb >> 4;
  const long sbase = (long)b * 2048;
  const int q0 = qt * 128;
  const int colbase = h * 128;
  const int qa_own = q0 + wave * 32 + (lane & 15);
  const int qb_own = qa_own + 16;

  half8 qfa[4], qfb[4];
  {
    const _Float16 hs = (_Float16)0.08838834764831845f;
    const _Float16* qpa = Q + (sbase + qa_own) * 2048 + colbase + g * 8;
    const _Float16* qpb = Q + (sbase + qb_own) * 2048 + colbase + g * 8;
#pragma unroll
    for (int c = 0; c < 4; ++c) {
      qfa[c] = (*reinterpret_cast<const half8*>(qpa + c * 32)) * hs;
      qfb[c] = (*reinterpret_cast<const half8*>(qpb + c * 32)) * hs;
    }
  }
  f32x4 oa[8] = {}, ob[8] = {};
  float ma = -INFINITY, la = 0.f, mb = -INFINITY, lb = 0.f;
  float mra[4] = {-INFINITY, -INFINITY, -INFINITY, -INFINITY};
  float mrb[4] = {-INFINITY, -INFINITY, -INFINITY, -INFINITY};
  const int nt = 2 * qt + 2;

  int k_kr[4], k_cs[4], v_vr[4], v_cs[4];
#pragma unroll
  for (int j = 0; j < 4; ++j) {
    int ci = j * 256 + tid;
    k_kr[j] = ci >> 4;
    k_cs[j] = (ci & 15) ^ (k_kr[j] & 7);
    v_vr[j] = ci >> 3;
    v_cs[j] = (ci & 7) ^ (v_vr[j] & 7);
  }
  auto stage = [&](int k0, int buf) {
#pragma unroll
    for (int j = 0; j < 4; ++j)
      gload16(Kr + (sbase + k0 + k_kr[j]) * 2048 + colbase + k_cs[j] * 8,
              Ks[buf] + (j * 256 + tid) * 16);
#pragma unroll
    for (int j = 0; j < 4; ++j)
      gload16(VT + (long)(colbase + v_vr[j]) * 4096 + sbase + k0 + v_cs[j] * 8,
              Vs[buf] + (j * 256 + tid) * 16);
  };

  stage(0, 0);
  __syncthreads();

  for (int t = 0; t < nt; ++t) {
    const int cur = t & 1;
    const int k0 = t * 64;
    if (t + 1 < nt) stage(k0 + 64, cur ^ 1);

    const bool active = !(t == nt - 1 && wave < 2);
    if (active) {
      // ---- S^T = K Q^T for both q-groups (K-frag read once) ----
      f32x4 sa[4] = {}, sb[4] = {};
      __builtin_amdgcn_s_setprio(1);
#pragma unroll
      for (int n = 0; n < 4; ++n) {
        int key = n * 16 + (lane & 15);
#pragma unroll
        for (int c = 0; c < 4; ++c) {
          half8 kf = *reinterpret_cast<const half8*>(
              Ks[cur] + key * 256 + (((c * 4 + g) ^ (key & 7)) * 16));
          sa[n] = __builtin_amdgcn_mfma_f32_16x16x32_f16(kf, qfa[c], sa[n], 0, 0, 0);
          sb[n] = __builtin_amdgcn_mfma_f32_16x16x32_f16(kf, qfb[c], sb[n], 0, 0, 0);
        }
      }
      __builtin_amdgcn_s_setprio(0);

      // ---- causal mask (last two tiles only) ----
      if (t >= nt - 2) {
        int kba = k0 + g * 4 - qa_own;
        int kbb = kba - 16;
#pragma unroll
        for (int n = 0; n < 4; ++n)
#pragma unroll
          for (int r = 0; r < 4; ++r) {
            if (kba + n * 16 + r > 0) sa[n][r] = -INFINITY;
            if (kbb + n * 16 + r > 0) sb[n][r] = -INFINITY;
          }
      }

      // ---- online softmax, defer-max ----
      float mxa = fmaxf(fmaxf(fmaxf(sa[0][0], sa[0][1]), fmaxf(sa[0][2], sa[0][3])),
                        fmaxf(fmaxf(sa[1][0], sa[1][1]), fmaxf(sa[1][2], sa[1][3])));
      mxa = fmaxf(mxa, fmaxf(fmaxf(fmaxf(sa[2][0], sa[2][1]), fmaxf(sa[2][2], sa[2][3])),
                             fmaxf(fmaxf(sa[3][0], sa[3][1]), fmaxf(sa[3][2], sa[3][3]))));
      float mxb = fmaxf(fmaxf(fmaxf(sb[0][0], sb[0][1]), fmaxf(sb[0][2], sb[0][3])),
                        fmaxf(fmaxf(sb[1][0], sb[1][1]), fmaxf(sb[1][2], sb[1][3])));
      mxb = fmaxf(mxb, fmaxf(fmaxf(fmaxf(sb[2][0], sb[2][1]), fmaxf(sb[2][2], sb[2][3])),
                             fmaxf(fmaxf(sb[3][0], sb[3][1]), fmaxf(sb[3][2], sb[3][3]))));
      mxa = fmaxf(mxa, __shfl_xor(mxa, 16));
      mxa = fmaxf(mxa, __shfl_xor(mxa, 32));
      mxb = fmaxf(mxb, __shfl_xor(mxb, 16));
      mxb = fmaxf(mxb, __shfl_xor(mxb, 32));

      bool need = (mxa > ma + 8.f) || (mxb > mb + 8.f);
      if (__any(need)) {
        float mna = fmaxf(ma, mxa), mnb = fmaxf(mb, mxb);
        float alfa[4], alfb[4];
#pragma unroll
        for (int r = 0; r < 4; ++r) {
          float va = __shfl(mna, (lane & 48) | (g * 4 + r));
          alfa[r] = __expf(mra[r] - va);
          mra[r] = va;
          float vb = __shfl(mnb, (lane & 48) | (g * 4 + r));
          alfb[r] = __expf(mrb[r] - vb);
          mrb[r] = vb;
        }
        la *= __expf(ma - mna);
        lb *= __expf(mb - mnb);
        ma = mna;
        mb = mnb;
#pragma unroll
        for (int n = 0; n < 8; ++n) {
          f32x4 ta = oa[n], tb = ob[n];
          ta[0] *= alfa[0]; ta[1] *= alfa[1]; ta[2] *= alfa[2]; ta[3] *= alfa[3];
          tb[0] *= alfb[0]; tb[1] *= alfb[1]; tb[2] *= alfb[2]; tb[3] *= alfb[3];
          oa[n] = ta; ob[n] = tb;
        }
      }

      float pea[4][4], peb[4][4];
#pragma unroll
      for (int n = 0; n < 4; ++n)
#pragma unroll
        for (int r = 0; r < 4; ++r) {
          pea[n][r] = __expf(sa[n][r] - ma);
          peb[n][r] = __expf(sb[n][r] - mb);
        }
      {
        float lsa = 0.f, lsb = 0.f;
#pragma unroll
        for (int n = 0; n < 4; ++n)
#pragma unroll
          for (int r = 0; r < 4; ++r) { lsa += pea[n][r]; lsb += peb[n][r]; }
        lsa += __shfl_xor(lsa, 16);
        lsa += __shfl_xor(lsa, 32);
        lsb += __shfl_xor(lsb, 16);
        lsb += __shfl_xor(lsb, 32);
        la += lsa;
        lb += lsb;
      }

      // ---- pack P to f16 PV A-fragments via permlane swaps ----
      half8 paa[2], pab[2];
      {
        unsigned loa[4], hia[4], lob[4], hib[4];
#pragma unroll
        for (int n = 0; n < 4; ++n) {
          loa[n] = __builtin_bit_cast(unsigned, __builtin_amdgcn_cvt_pkrtz(pea[n][0], pea[n][1]));
          hia[n] = __builtin_bit_cast(unsigned, __builtin_amdgcn_cvt_pkrtz(pea[n][2], pea[n][3]));
          lob[n] = __builtin_bit_cast(unsigned, __builtin_amdgcn_cvt_pkrtz(peb[n][0], peb[n][1]));
          hib[n] = __builtin_bit_cast(unsigned, __builtin_amdgcn_cvt_pkrtz(peb[n][2], peb[n][3]));
        }
#pragma unroll
        for (int ks = 0; ks < 2; ++ks) {
          unsigned al = loa[ks * 2], bl = loa[ks * 2 + 1];
          unsigned ah = hia[ks * 2], bh = hia[ks * 2 + 1];
          asm("v_permlane32_swap_b32 %0, %1" : "+v"(al), "+v"(bl));
          asm("v_permlane16_swap_b32 %0, %1" : "+v"(al), "+v"(bl));
          asm("v_permlane32_swap_b32 %0, %1" : "+v"(ah), "+v"(bh));
          asm("v_permlane16_swap_b32 %0, %1" : "+v"(ah), "+v"(bh));
          u32x4 w; w[0] = al; w[1] = ah; w[2] = bl; w[3] = bh;
          paa[ks] = __builtin_bit_cast(half8, w);
          unsigned al2 = lob[ks * 2], bl2 = lob[ks * 2 + 1];
          unsigned ah2 = hib[ks * 2], bh2 = hib[ks * 2 + 1];
          asm("v_permlane32_swap_b32 %0, %1" : "+v"(al2), "+v"(bl2));
          asm("v_permlane16_swap_b32 %0, %1" : "+v"(al2), "+v"(bl2));
          asm("v_permlane32_swap_b32 %0, %1" : "+v"(ah2), "+v"(bh2));
          asm("v_permlane16_swap_b32 %0, %1" : "+v"(ah2), "+v"(bh2));
          u32x4 w2; w2[0] = al2; w2[1] = ah2; w2[2] = bl2; w2[3] = bh2;
          pab[ks] = __builtin_bit_cast(half8, w2);
        }
      }

      // ---- O += P V (V-frag read once, feeds both groups) ----
      __builtin_amdgcn_s_setprio(1);
#pragma unroll
      for (int n = 0; n < 8; ++n) {
        int d = n * 16 + (lane & 15);
#pragma unroll
        for (int ks = 0; ks < 2; ++ks) {
          half8 vf = *reinterpret_cast<const half8*>(
              Vs[cur] + d * 128 + (((ks * 4 + g) ^ (d & 7)) * 16));
          oa[n] = __builtin_amdgcn_mfma_f32_16x16x32_f16(paa[ks], vf, oa[n], 0, 0, 0);
          ob[n] = __builtin_amdgcn_mfma_f32_16x16x32_f16(pab[ks], vf, ob[n], 0, 0, 0);
        }
      }
      __builtin_amdgcn_s_setprio(0);
    }
    __syncthreads();  // compute(cur) done everywhere + stage(next) drained
  }

  // ---- epilogue ----
  float lra[4], lrb[4];
#pragma unroll
  for (int r = 0; r < 4; ++r) {
    lra[r] = __shfl(la, (lane & 48) | (g * 4 + r));
    lrb[r] = __shfl(lb, (lane & 48) | (g * 4 + r));
  }
#pragma unroll
  for (int n = 0; n < 8; ++n) {
    int d = colbase + n * 16 + (lane & 15);
#pragma unroll
    for (int r = 0; r < 4; ++r) {
      int rowa = q0 + wave * 32 + (g << 2) + r;
      O[(sbase + rowa) * 2048 + d] = (_Float16)(oa[n][r] / lra[r]);
      O[(sbase + rowa + 16) * 2048 + d] = (_Float16)(ob[n][r] / lrb[r]);
    }
  }
}

extern "C" void kernel_launch(void* const* d_in, const int* in_sizes, int n_in,
                              void* d_out, int out_size, void* d_ws, size_t ws_size,
                              hipStream_t stream) {
  const float* x     = (const float*)d_in[0];
  const float* Wq_d  = (const float*)d_in[1];
  const float* Wkv_d = (const float*)d_in[2];
  const float* Wq_u  = (const float*)d_in[3];
  const float* Wk_u  = (const float*)d_in[4];
  const float* Wv_u  = (const float*)d_in[5];
  const float* Wo    = (const float*)d_in[6];
  char* ws = (char*)d_ws;
  _Float16* xb  = (_Float16*)(ws);              // [4096][2048] (reused as ao)
  _Float16* wdT = (_Float16*)(ws + 16777216);   // [1024][2048]; dead after down-GEMM -> trig table
  _Float16* wuT = (_Float16*)(ws + 20971520);   // 3x [2048][512]
  _Float16* woT = (_Float16*)(ws + 27262976);   // [2048][2048]
  _Float16* lat = (_Float16*)(ws + 35651584);   // [4096][1024]
  _Float16* qb  = (_Float16*)(ws + 44040192);   // [4096][2048]
  _Float16* kb  = (_Float16*)(ws + 60817408);   // [4096][2048]
  _Float16* vT  = (_Float16*)(ws + 77594624);   // [2048 d][4096 s]
  float*    tab = (float*)(ws + 16777216);      // 2048*128 fp32 = 1 MB (aliases wdT)
  _Float16* ao  = xb;

  conv_f16<<<8192, 256, 0, stream>>>(x, xb, 8388608);
  transpose_f16<<<dim3(16, 64), 256, 0, stream>>>(Wq_d, wdT, 2048, 512);
  transpose_f16<<<dim3(16, 64), 256, 0, stream>>>(Wkv_d, wdT + 512 * 2048, 2048, 512);
  transpose_f16<<<dim3(64, 16), 256, 0, stream>>>(Wq_u, wuT, 512, 2048);
  transpose_f16<<<dim3(64, 16), 256, 0, stream>>>(Wk_u, wuT + 2048 * 512, 512, 2048);
  transpose_f16<<<dim3(64, 16), 256, 0, stream>>>(Wv_u, wuT + 2 * 2048 * 512, 512, 2048);
  transpose_f16<<<dim3(64, 64), 256, 0, stream>>>(Wo, woT, 2048, 2048);

  // lat = x @ [Wq_d | Wkv_d]
  gemm_bt<false><<<dim3(8, 32), 256, 0, stream>>>(xb, 2048, wdT, 2048, lat, 1024, 2048);

  // wdT is now dead -> build trig table in its space
  trig_tab<<<512, 256, 0, stream>>>(tab);

  // q = lat_q @ Wq_u ; k = lat_kv @ Wk_u   (row-major outputs)
  gemm_bt<false><<<dim3(16, 32), 256, 0, stream>>>(lat, 1024, wuT, 512, qb, 2048, 512);
  gemm_bt<false><<<dim3(16, 32), 256, 0, stream>>>(lat + 512, 1024, wuT + 2048 * 512, 512, kb, 2048, 512);
  // vT[d][s] = Wv_u^T @ lat_kv^T  (transposed output, same FLOPs)
  gemm_bt<false><<<dim3(32, 16), 256, 0, stream>>>(wuT + 2 * 2048 * 512, 512, lat + 512, 1024, vT, 4096, 512);

  rope_k<<<32768, 256, 0, stream>>>(qb, kb, tab);
  attn_fused<<<dim3(16, 16, 2), 256, 0, stream>>>(qb, kb, vT, ao);

  gemm_bt<true><<<dim3(16, 32), 256, 0, stream>>>(ao, 2048, woT, 2048, d_out, 2048, 2048);
}